// Round 4
// baseline (935.397 us; speedup 1.0000x reference)
//
#include <hip/hip_runtime.h>
#include <hip/hip_bf16.h>
#include <math.h>

typedef __attribute__((ext_vector_type(8))) short short8;
typedef __attribute__((ext_vector_type(4))) short sv4;
typedef __attribute__((ext_vector_type(4))) float f32x4;
typedef unsigned int u32;

#define BT_ 384
#define N_ 716
#define C_ 256
#define H_ 8
#define D_ 32
#define MROWS (BT_ * N_)   /* 274944 */
#define SCALE_ 0.17677669529663687f  /* 32^-0.5 */
#define INVN_ (1.0f / 716.0f)

__device__ __forceinline__ void gload_lds16(const void* g, void* l) {
    __builtin_amdgcn_global_load_lds(
        (const __attribute__((address_space(1))) u32*)g,
        (__attribute__((address_space(3))) u32*)l, 16, 0, 0);
}

// ---------------------------------------------------------------------------
// Assemble bf16 weight matrices + fused qkv bias. Wqkv_b[768][256], Wo_b[256][256]
// ---------------------------------------------------------------------------
__global__ void prep_weights(const float* __restrict__ Wq, const float* __restrict__ bq,
                             const float* __restrict__ Wk, const float* __restrict__ bk,
                             const float* __restrict__ Wv, const float* __restrict__ bv,
                             const float* __restrict__ Wo,
                             __hip_bfloat16* __restrict__ wqkv, float* __restrict__ bqkv,
                             __hip_bfloat16* __restrict__ wo) {
    int idx = blockIdx.x * 256 + threadIdx.x;
    if (idx < 768 * 256) {
        int o = idx >> 8, c = idx & 255;
        const float* W = (o < 256) ? Wq : ((o < 512) ? Wk : Wv);
        int oo = o & 255;
        wqkv[idx] = __float2bfloat16(W[oo * 256 + c]);
    }
    if (idx < 256 * 256) wo[idx] = __float2bfloat16(Wo[idx]);
    if (idx < 768) bqkv[idx] = (idx < 256) ? bq[idx] : ((idx < 512) ? bk[idx - 256] : bv[idx - 512]);
}

// ---------------------------------------------------------------------------
// x fp32 -> bf16 (vectorized float4/short4), plus per-(bt,channel) col sums
// grid (384, 4), block 256. thread = (row-group t>>6, channel-quad t&63).
// ---------------------------------------------------------------------------
__global__ __launch_bounds__(256)
void convert_x(const float* __restrict__ x, __hip_bfloat16* __restrict__ xb,
               float* __restrict__ msum) {
    int bt = blockIdx.x, chunk = blockIdx.y;
    int t = threadIdx.x;
    int c4 = (t & 63) * 4;
    int r0 = t >> 6;
    size_t base = ((size_t)bt * N_ + (size_t)chunk * 179) * C_;
    float s0 = 0.f, s1 = 0.f, s2 = 0.f, s3 = 0.f;
    for (int r = r0; r < 179; r += 4) {
        float4 f = *(const float4*)&x[base + (size_t)r * C_ + c4];
        union { sv4 v; __hip_bfloat16 h[4]; } u;
        u.h[0] = __float2bfloat16(f.x);
        u.h[1] = __float2bfloat16(f.y);
        u.h[2] = __float2bfloat16(f.z);
        u.h[3] = __float2bfloat16(f.w);
        *(sv4*)&xb[base + (size_t)r * C_ + c4] = u.v;
        s0 += f.x; s1 += f.y; s2 += f.z; s3 += f.w;
    }
    atomicAdd(&msum[bt * C_ + c4 + 0], s0);
    atomicAdd(&msum[bt * C_ + c4 + 1], s1);
    atomicAdd(&msum[bt * C_ + c4 + 2], s2);
    atomicAdd(&msum[bt * C_ + c4 + 3], s3);
}

// ---------------------------------------------------------------------------
// Grouped 2-layer MLP -> per-channel 3-tap conv weights rw[bt][768]
// ---------------------------------------------------------------------------
__global__ __launch_bounds__(256)
void mlp_rw(const float* __restrict__ msum, const float* __restrict__ w1,
            const float* __restrict__ b1, const float* __restrict__ w2,
            const float* __restrict__ b2, float* __restrict__ rw) {
    int bt = blockIdx.x;
    int t = threadIdx.x;
    __shared__ float m_l[256];
    __shared__ float h1_l[256];
    m_l[t] = msum[bt * 256 + t] * INVN_;
    __syncthreads();
    int g = t >> 5;
    float a = b1[t];
    #pragma unroll
    for (int i = 0; i < 32; ++i) a += m_l[g * 32 + i] * w1[t * 32 + i];
    h1_l[t] = 0.5f * a * (1.0f + erff(a * 0.70710678118654752f));
    __syncthreads();
    for (int o = t; o < 768; o += 256) {
        int gg = o / 96;
        float s = b2[o];
        #pragma unroll
        for (int i = 0; i < 32; ++i) s += h1_l[gg * 32 + i] * w2[o * 32 + i];
        rw[bt * 768 + o] = s;
    }
}

// ---------------------------------------------------------------------------
// bf16 GEMM, B-transposed: out[m][o] = sum_k A[m][k] * Bm[o][k] + bias[o]
// K fixed = 256. 128x128 tile, BK=64, 4 waves. Double-buffered LDS, pipelined:
// one __syncthreads per K-step, next tile's global_load_lds issued before the
// current tile's compute so load latency hides under MFMA (T3-minimum).
// XCD-aware bijective block swizzle + LDS XOR swizzle (pre-swizzled source).
// grid (GRIDX, 2148), block 256.
// ---------------------------------------------------------------------------
template<int NCOLS, int GRIDX, bool OUT_BF16>
__global__ __launch_bounds__(256)
void gemm_bt(const __hip_bfloat16* __restrict__ A, const __hip_bfloat16* __restrict__ Bm,
             const float* __restrict__ bias, void* __restrict__ outp) {
    __shared__ __align__(16) __hip_bfloat16 As[2][128 * 64];
    __shared__ __align__(16) __hip_bfloat16 Bs[2][128 * 64];
    constexpr int NWG = GRIDX * (MROWS / 128);
    constexpr int PER = NWG / 8;                 // NWG % 8 == 0 for both instances
    const int lin = blockIdx.y * GRIDX + blockIdx.x;
    const int tt  = (lin & 7) * PER + (lin >> 3);
    const int bx = tt % GRIDX, by = tt / GRIDX;

    const int tid  = threadIdx.x;
    const int lane = tid & 63;
    const int wave = tid >> 6;
    const int wr = wave >> 1, wc = wave & 1;
    const int l15 = lane & 15, lq = lane >> 4;
    const size_t rowBase = (size_t)by * 128;
    const int    colBase = bx * 128;
    const int lrow = lane >> 3;                // 0..7 row within 8-row stripe
    const int gsl  = ((lane & 7) ^ lrow) * 8;  // XOR-swizzled source slot (bf16 elems)

    const __hip_bfloat16* Abase = A  + (rowBase + wave * 32 + lrow) * 256 + gsl;
    const __hip_bfloat16* Bbase = Bm + (size_t)(colBase + wave * 32 + lrow) * 256 + gsl;

    auto stage = [&](int ks, int buf) {
        #pragma unroll
        for (int i = 0; i < 4; ++i) {
            int rb = wave * 32 + i * 8;
            gload_lds16(Abase + (size_t)i * 8 * 256 + ks, &As[buf][rb * 64]);
            gload_lds16(Bbase + (size_t)i * 8 * 256 + ks, &Bs[buf][rb * 64]);
        }
    };

    f32x4 acc[4][4] = {};

    stage(0, 0);
    __syncthreads();

    int cur = 0;
    #pragma unroll
    for (int t = 0; t < 4; ++t) {
        if (t < 3) stage((t + 1) * 64, cur ^ 1);
        #pragma unroll
        for (int kk = 0; kk < 64; kk += 32) {
            const int sb = (kk >> 3) + lq;           // needed global 16B-slot
            const int sl = ((sb ^ (l15 & 7)) * 8);   // swizzled LDS slot (elems)
            short8 af[4], bf[4];
            #pragma unroll
            for (int m = 0; m < 4; ++m)
                af[m] = *(const short8*)&As[cur][(wr * 64 + m * 16 + l15) * 64 + sl];
            #pragma unroll
            for (int n = 0; n < 4; ++n)
                bf[n] = *(const short8*)&Bs[cur][(wc * 64 + n * 16 + l15) * 64 + sl];
            #pragma unroll
            for (int m = 0; m < 4; ++m)
                #pragma unroll
                for (int n = 0; n < 4; ++n)
                    acc[m][n] = __builtin_amdgcn_mfma_f32_16x16x32_bf16(af[m], bf[n], acc[m][n], 0, 0, 0);
        }
        __syncthreads();
        cur ^= 1;
    }

    // epilogue: C/D layout col = lane&15, row = (lane>>4)*4 + j
    #pragma unroll
    for (int n = 0; n < 4; ++n) {
        int col = colBase + wc * 64 + n * 16 + l15;
        float bv = bias[col];
        #pragma unroll
        for (int m = 0; m < 4; ++m) {
            size_t row0 = rowBase + wr * 64 + m * 16 + lq * 4;
            #pragma unroll
            for (int j = 0; j < 4; ++j) {
                float val = acc[m][n][j] + bv;
                if (OUT_BF16)
                    ((__hip_bfloat16*)outp)[(row0 + j) * NCOLS + col] = __float2bfloat16(val);
                else
                    ((float*)outp)[(row0 + j) * NCOLS + col] = val;
            }
        }
    }
}

// ---------------------------------------------------------------------------
// Per-(bt,h): kv2[d][e] = (sum_n k[n,d] v[n,e]) * scale/N - scale*kmean[d]*vmean[e]
// Output TRANSPOSED as bf16: kv2t[bh][e][d]  (B^T fragment layout for MFMA)
// ---------------------------------------------------------------------------
__global__ __launch_bounds__(256)
void reduce_kv(const __hip_bfloat16* __restrict__ qkv, __hip_bfloat16* __restrict__ kv2t,
               float* __restrict__ vmeanb) {
    int bh = blockIdx.x;
    int bt = bh >> 3, h = bh & 7;
    int t = threadIdx.x;
    int e = t & 31, d0 = t >> 5;
    __shared__ __hip_bfloat16 ks[64][32];
    __shared__ __hip_bfloat16 vs[64][32];
    float acc[4] = {0.f, 0.f, 0.f, 0.f};
    float ksum[4] = {0.f, 0.f, 0.f, 0.f};
    float vsum = 0.f;
    const size_t rowbase = (size_t)bt * N_;
    for (int n0 = 0; n0 < N_; n0 += 64) {
        int nn = (N_ - n0 < 64) ? (N_ - n0) : 64;
        for (int i = t; i < nn * 32; i += 256) {
            int r = i >> 5, cc = i & 31;
            size_t row = (rowbase + n0 + r) * 768;
            ks[r][cc] = qkv[row + 256 + h * 32 + cc];
            vs[r][cc] = qkv[row + 512 + h * 32 + cc];
        }
        __syncthreads();
        for (int n = 0; n < nn; ++n) {
            float vv = __bfloat162float(vs[n][e]);
            #pragma unroll
            for (int r = 0; r < 4; ++r) {
                float kk = __bfloat162float(ks[n][d0 + 8 * r]);
                acc[r]  += kk * vv;
                ksum[r] += kk;
            }
            vsum += vv;
        }
        __syncthreads();
    }
    __shared__ float km[32];
    __shared__ float vm[32];
    if (e == 0) {
        #pragma unroll
        for (int r = 0; r < 4; ++r) km[d0 + 8 * r] = ksum[r] * INVN_;
    }
    if (d0 == 0) vm[e] = vsum * INVN_;
    __syncthreads();
    float vme = vm[e];
    #pragma unroll
    for (int r = 0; r < 4; ++r) {
        int d = d0 + 8 * r;
        float val = acc[r] * (SCALE_ * INVN_) - SCALE_ * km[d] * vme;
        kv2t[((size_t)bh * 32 + e) * 32 + d] = __float2bfloat16(val);
    }
    if (d0 == 0) vmeanb[bh * 32 + e] = vme;
}

// ---------------------------------------------------------------------------
// fuse_z2: per (bt, 64-row chunk):
//   phase 1 (MFMA): attn[64][256] = q @ kv2t^T + vmean  -> LDS (bf16)
//   phase 2: Z[n][c] = attn[n][c] + rw0*v[n-1][c] + rw1*v[n][c] + rw2*v[n+1][c]
// grid (384, 12), block 256 (4 waves). LDS = 32KB attn + 16KB kv2t = 48KB.
// ---------------------------------------------------------------------------
__global__ __launch_bounds__(256)
void fuse_z2(const __hip_bfloat16* __restrict__ qkv, const __hip_bfloat16* __restrict__ kv2t,
             const float* __restrict__ vmeanb, const float* __restrict__ rw,
             __hip_bfloat16* __restrict__ Z) {
    __shared__ __align__(16) __hip_bfloat16 attn[64][256];
    __shared__ __align__(16) __hip_bfloat16 kvl[8192];
    int bt = blockIdx.x;
    int n0 = blockIdx.y * 64;
    int rows = (N_ - n0 < 64) ? (N_ - n0) : 64;
    int t = threadIdx.x;
    const size_t rowbase = (size_t)bt * N_;

    {
        const __hip_bfloat16* src = kv2t + (size_t)bt * 8192;
        #pragma unroll
        for (int i = 0; i < 4; ++i) {
            int off = (t + i * 256) * 8;
            *(short8*)&kvl[off] = *(const short8*)&src[off];
        }
    }
    __syncthreads();

    {
        int lane = t & 63, wave = t >> 6;
        int l15 = lane & 15, lq = lane >> 4;
        int r0 = wave * 16;
        int gn = n0 + r0 + l15; if (gn > N_ - 1) gn = N_ - 1;
        const __hip_bfloat16* qrow = qkv + (rowbase + gn) * 768;
        #pragma unroll
        for (int h = 0; h < 8; ++h) {
            short8 af = *(const short8*)&qrow[h * 32 + lq * 8];
            #pragma unroll
            for (int half = 0; half < 2; ++half) {
                short8 bf = *(const short8*)&kvl[h * 1024 + (half * 16 + l15) * 32 + lq * 8];
                f32x4 acc = {};
                acc = __builtin_amdgcn_mfma_f32_16x16x32_bf16(af, bf, acc, 0, 0, 0);
                int col = h * 32 + half * 16 + l15;
                float vm = vmeanb[bt * 256 + col];
                #pragma unroll
                for (int j = 0; j < 4; ++j)
                    attn[r0 + lq * 4 + j][col] = __float2bfloat16(acc[j] + vm);
            }
        }
    }
    __syncthreads();

    {
        int c = t;
        float r0w = rw[bt * 768 + c * 3 + 0];
        float r1w = rw[bt * 768 + c * 3 + 1];
        float r2w = rw[bt * 768 + c * 3 + 2];
        const __hip_bfloat16* vb = qkv + rowbase * 768 + 512 + c;
        float vprev = (n0 > 0) ? __bfloat162float(vb[(size_t)(n0 - 1) * 768]) : 0.0f;
        float vcur  = __bfloat162float(vb[(size_t)n0 * 768]);
        #pragma unroll 4
        for (int r = 0; r < rows; ++r) {
            int gn = n0 + r;
            float vnext = (gn + 1 < N_) ? __bfloat162float(vb[(size_t)(gn + 1) * 768]) : 0.0f;
            float s = __bfloat162float(attn[r][c]) + r0w * vprev + r1w * vcur + r2w * vnext;
            Z[(rowbase + gn) * 256 + c] = __float2bfloat16(s);
            vprev = vcur; vcur = vnext;
        }
    }
}

// ---------------------------------------------------------------------------
extern "C" void kernel_launch(void* const* d_in, const int* in_sizes, int n_in,
                              void* d_out, int out_size, void* d_ws, size_t ws_size,
                              hipStream_t stream) {
    (void)in_sizes; (void)n_in; (void)out_size; (void)ws_size;
    const float* x  = (const float*)d_in[0];
    const float* Wq = (const float*)d_in[1];  const float* bq = (const float*)d_in[2];
    const float* Wk = (const float*)d_in[3];  const float* bk = (const float*)d_in[4];
    const float* Wv = (const float*)d_in[5];  const float* bv = (const float*)d_in[6];
    const float* Wo = (const float*)d_in[7];  const float* bo = (const float*)d_in[8];
    const float* w1 = (const float*)d_in[9];  const float* b1 = (const float*)d_in[10];
    const float* w2 = (const float*)d_in[11]; const float* b2 = (const float*)d_in[12];
    float* out = (float*)d_out;

    char* ws = (char*)d_ws;
    size_t off = 0;
    auto take = [&](size_t bytes) -> char* {
        char* p = ws + off;
        off = (off + bytes + 255) & ~(size_t)255;
        return p;
    };

    __hip_bfloat16* qkv   = (__hip_bfloat16*)take((size_t)MROWS * 768 * 2);
    __hip_bfloat16* xb    = (__hip_bfloat16*)take((size_t)MROWS * 256 * 2);
    __hip_bfloat16* Zbuf  = xb;  // alias: xb dead after gemm_qkv, reused for Z
    __hip_bfloat16* wqkv  = (__hip_bfloat16*)take(768 * 256 * 2);
    __hip_bfloat16* wo    = (__hip_bfloat16*)take(256 * 256 * 2);
    float* bqkv   = (float*)take(768 * 4);
    float* msum   = (float*)take(384 * 256 * 4);
    float* rw     = (float*)take(384 * 768 * 4);
    __hip_bfloat16* kv2t = (__hip_bfloat16*)take((size_t)384 * 8192 * 2);
    float* vmeanb = (float*)take(384 * 256 * 4);

    hipMemsetAsync(msum, 0, 384 * 256 * 4, stream);

    prep_weights<<<768, 256, 0, stream>>>(Wq, bq, Wk, bk, Wv, bv, Wo, wqkv, bqkv, wo);
    convert_x<<<dim3(384, 4), 256, 0, stream>>>(x, xb, msum);
    mlp_rw<<<384, 256, 0, stream>>>(msum, w1, b1, w2, b2, rw);
    // QKV projection: [274944,256] x [768,256]^T -> bf16 qkv, bias fused
    gemm_bt<768, 6, true><<<dim3(6, 2148), 256, 0, stream>>>(xb, wqkv, bqkv, qkv);
    reduce_kv<<<3072, 256, 0, stream>>>(qkv, kv2t, vmeanb);
    fuse_z2<<<dim3(384, 12), 256, 0, stream>>>(qkv, kv2t, vmeanb, rw, Zbuf);
    // Output projection: [274944,256] x [256,256]^T -> f32 out, bias fused
    gemm_bt<256, 2, false><<<dim3(2, 2148), 256, 0, stream>>>(Zbuf, wo, bo, out);
}

// Round 5
// 906.288 us; speedup vs baseline: 1.0321x; 1.0321x over previous
//
#include <hip/hip_runtime.h>
#include <hip/hip_bf16.h>
#include <math.h>

typedef __attribute__((ext_vector_type(8))) short short8;
typedef __attribute__((ext_vector_type(4))) short sv4;
typedef __attribute__((ext_vector_type(4))) float f32x4;
typedef unsigned int u32;

#define BT_ 384
#define N_ 716
#define C_ 256
#define H_ 8
#define D_ 32
#define MROWS (BT_ * N_)   /* 274944 */
#define SCALE_ 0.17677669529663687f  /* 32^-0.5 */
#define INVN_ (1.0f / 716.0f)

__device__ __forceinline__ void gload_lds16(const void* g, void* l) {
    __builtin_amdgcn_global_load_lds(
        (const __attribute__((address_space(1))) u32*)g,
        (__attribute__((address_space(3))) u32*)l, 16, 0, 0);
}

template<int N>
__device__ __forceinline__ void waitcnt_vm() {
    if constexpr (N == 0)       asm volatile("s_waitcnt vmcnt(0)" ::: "memory");
    else if constexpr (N == 4)  asm volatile("s_waitcnt vmcnt(4)" ::: "memory");
    else if constexpr (N == 8)  asm volatile("s_waitcnt vmcnt(8)" ::: "memory");
    else                        asm volatile("s_waitcnt vmcnt(12)" ::: "memory");
}

// ---------------------------------------------------------------------------
// Assemble bf16 weight matrices + fused qkv bias. Wqkv_b[768][256], Wo_b[256][256]
// ---------------------------------------------------------------------------
__global__ void prep_weights(const float* __restrict__ Wq, const float* __restrict__ bq,
                             const float* __restrict__ Wk, const float* __restrict__ bk,
                             const float* __restrict__ Wv, const float* __restrict__ bv,
                             const float* __restrict__ Wo,
                             __hip_bfloat16* __restrict__ wqkv, float* __restrict__ bqkv,
                             __hip_bfloat16* __restrict__ wo) {
    int idx = blockIdx.x * 256 + threadIdx.x;
    if (idx < 768 * 256) {
        int o = idx >> 8, c = idx & 255;
        const float* W = (o < 256) ? Wq : ((o < 512) ? Wk : Wv);
        int oo = o & 255;
        wqkv[idx] = __float2bfloat16(W[oo * 256 + c]);
    }
    if (idx < 256 * 256) wo[idx] = __float2bfloat16(Wo[idx]);
    if (idx < 768) bqkv[idx] = (idx < 256) ? bq[idx] : ((idx < 512) ? bk[idx - 256] : bv[idx - 512]);
}

// ---------------------------------------------------------------------------
// x fp32 -> bf16 (vectorized float4/short4), plus per-(bt,channel) col sums
// grid (384, 4), block 256.
// ---------------------------------------------------------------------------
__global__ __launch_bounds__(256)
void convert_x(const float* __restrict__ x, __hip_bfloat16* __restrict__ xb,
               float* __restrict__ msum) {
    int bt = blockIdx.x, chunk = blockIdx.y;
    int t = threadIdx.x;
    int c4 = (t & 63) * 4;
    int r0 = t >> 6;
    size_t base = ((size_t)bt * N_ + (size_t)chunk * 179) * C_;
    float s0 = 0.f, s1 = 0.f, s2 = 0.f, s3 = 0.f;
    for (int r = r0; r < 179; r += 4) {
        float4 f = *(const float4*)&x[base + (size_t)r * C_ + c4];
        union { sv4 v; __hip_bfloat16 h[4]; } u;
        u.h[0] = __float2bfloat16(f.x);
        u.h[1] = __float2bfloat16(f.y);
        u.h[2] = __float2bfloat16(f.z);
        u.h[3] = __float2bfloat16(f.w);
        *(sv4*)&xb[base + (size_t)r * C_ + c4] = u.v;
        s0 += f.x; s1 += f.y; s2 += f.z; s3 += f.w;
    }
    atomicAdd(&msum[bt * C_ + c4 + 0], s0);
    atomicAdd(&msum[bt * C_ + c4 + 1], s1);
    atomicAdd(&msum[bt * C_ + c4 + 2], s2);
    atomicAdd(&msum[bt * C_ + c4 + 3], s3);
}

// ---------------------------------------------------------------------------
// Grouped 2-layer MLP -> per-channel 3-tap conv weights rw[bt][768]
// ---------------------------------------------------------------------------
__global__ __launch_bounds__(256)
void mlp_rw(const float* __restrict__ msum, const float* __restrict__ w1,
            const float* __restrict__ b1, const float* __restrict__ w2,
            const float* __restrict__ b2, float* __restrict__ rw) {
    int bt = blockIdx.x;
    int t = threadIdx.x;
    __shared__ float m_l[256];
    __shared__ float h1_l[256];
    m_l[t] = msum[bt * 256 + t] * INVN_;
    __syncthreads();
    int g = t >> 5;
    float a = b1[t];
    #pragma unroll
    for (int i = 0; i < 32; ++i) a += m_l[g * 32 + i] * w1[t * 32 + i];
    h1_l[t] = 0.5f * a * (1.0f + erff(a * 0.70710678118654752f));
    __syncthreads();
    for (int o = t; o < 768; o += 256) {
        int gg = o / 96;
        float s = b2[o];
        #pragma unroll
        for (int i = 0; i < 32; ++i) s += h1_l[gg * 32 + i] * w2[o * 32 + i];
        rw[bt * 768 + o] = s;
    }
}

// ---------------------------------------------------------------------------
// Deep-K bf16 GEMM, B-transposed: out[m][o] = sum_k A[m][k]*Bm[o][k] + bias[o]
// K=256 fully resident in LDS (A 64KB + B 64KB). 512 threads = 8 waves,
// tile 128x128, wave tile 64x32. All 16 global_load_lds per wave issued
// up-front in K order; per K-chunk: counted s_waitcnt vmcnt(12-4ks) + raw
// s_barrier (no full drain, no WAR barriers - LDS written once).
// XCD-aware bijective block swizzle + LDS XOR swizzle (pre-swizzled source).
// grid (GRIDX, 2148), block 512.
// ---------------------------------------------------------------------------
template<int NCOLS, int GRIDX, bool OUT_BF16>
__global__ __launch_bounds__(512, 1)
void gemm_deepk(const __hip_bfloat16* __restrict__ A, const __hip_bfloat16* __restrict__ Bm,
                const float* __restrict__ bias, void* __restrict__ outp) {
    __shared__ __align__(16) __hip_bfloat16 As[4][128 * 64];
    __shared__ __align__(16) __hip_bfloat16 Bs[4][128 * 64];
    constexpr int NWG = GRIDX * (MROWS / 128);
    constexpr int PER = NWG / 8;
    const int lin = blockIdx.y * GRIDX + blockIdx.x;
    const int tt  = (lin & 7) * PER + (lin >> 3);
    const int bx = tt % GRIDX, by = tt / GRIDX;

    const int tid  = threadIdx.x;
    const int lane = tid & 63;
    const int wave = tid >> 6;           // 0..7
    const int wr = wave & 1;             // row half (64 rows)
    const int wc = wave >> 1;            // col quarter (32 cols)
    const int l15 = lane & 15, lq = lane >> 4;
    const size_t rowBase = (size_t)by * 128;
    const int    colBase = bx * 128;
    const int lrow = lane >> 3;                 // 0..7
    const int gsl  = ((lane & 7) ^ lrow) * 8;   // XOR-swizzled source slot

    // ---- one-shot staging: 16 loads per wave, issued in K-chunk order ----
    const __hip_bfloat16* Ab = A  + (rowBase + wave * 16 + lrow) * 256 + gsl;
    const __hip_bfloat16* Bb = Bm + (size_t)(colBase + wave * 16 + lrow) * 256 + gsl;
    #pragma unroll
    for (int ks = 0; ks < 4; ++ks) {
        #pragma unroll
        for (int i = 0; i < 2; ++i)
            gload_lds16(Ab + (size_t)i * 8 * 256 + ks * 64, &As[ks][(wave * 16 + i * 8) * 64]);
        #pragma unroll
        for (int i = 0; i < 2; ++i)
            gload_lds16(Bb + (size_t)i * 8 * 256 + ks * 64, &Bs[ks][(wave * 16 + i * 8) * 64]);
    }

    f32x4 acc[4][2] = {};

    #pragma unroll
    for (int ks = 0; ks < 4; ++ks) {
        // wait until this wave's chunks 0..ks have landed; barrier makes it global
        if (ks == 0) waitcnt_vm<12>();
        else if (ks == 1) waitcnt_vm<8>();
        else if (ks == 2) waitcnt_vm<4>();
        else waitcnt_vm<0>();
        __builtin_amdgcn_s_barrier();
        __builtin_amdgcn_sched_barrier(0);
        #pragma unroll
        for (int kk = 0; kk < 64; kk += 32) {
            const int sb = (kk >> 3) + lq;
            const int sl = ((sb ^ (l15 & 7)) * 8);
            short8 af[4], bf[2];
            #pragma unroll
            for (int m = 0; m < 4; ++m)
                af[m] = *(const short8*)&As[ks][(wr * 64 + m * 16 + l15) * 64 + sl];
            #pragma unroll
            for (int n = 0; n < 2; ++n)
                bf[n] = *(const short8*)&Bs[ks][(wc * 32 + n * 16 + l15) * 64 + sl];
            #pragma unroll
            for (int m = 0; m < 4; ++m)
                #pragma unroll
                for (int n = 0; n < 2; ++n)
                    acc[m][n] = __builtin_amdgcn_mfma_f32_16x16x32_bf16(af[m], bf[n], acc[m][n], 0, 0, 0);
        }
    }

    // epilogue: C/D layout col = lane&15, row = (lane>>4)*4 + j
    #pragma unroll
    for (int n = 0; n < 2; ++n) {
        int col = colBase + wc * 32 + n * 16 + l15;
        float bv = bias[col];
        #pragma unroll
        for (int m = 0; m < 4; ++m) {
            size_t row0 = rowBase + wr * 64 + m * 16 + lq * 4;
            #pragma unroll
            for (int j = 0; j < 4; ++j) {
                float val = acc[m][n][j] + bv;
                if (OUT_BF16)
                    ((__hip_bfloat16*)outp)[(row0 + j) * NCOLS + col] = __float2bfloat16(val);
                else
                    ((float*)outp)[(row0 + j) * NCOLS + col] = val;
            }
        }
    }
}

// ---------------------------------------------------------------------------
// Per-(bt, head-pair): kv2t[bh][e][d] (bf16) and vmean. 512 threads cover two
// adjacent heads (full 128B cache lines on k/v reads). grid 1536 = bt*4 + hp.
// ---------------------------------------------------------------------------
__global__ __launch_bounds__(512)
void reduce_kv(const __hip_bfloat16* __restrict__ qkv, __hip_bfloat16* __restrict__ kv2t,
               float* __restrict__ vmeanb) {
    int blk = blockIdx.x;
    int bt = blk >> 2, hp = blk & 3;          // head pair: heads 2hp, 2hp+1
    int t = threadIdx.x;
    int hh = t >> 8;                          // 0/1 within pair
    int ti = t & 255;
    int e = ti & 31, d0 = ti >> 5;
    __shared__ __hip_bfloat16 ks[64][64];
    __shared__ __hip_bfloat16 vs[64][64];
    float acc[4] = {0.f, 0.f, 0.f, 0.f};
    float ksum[4] = {0.f, 0.f, 0.f, 0.f};
    float vsum = 0.f;
    const size_t rowbase = (size_t)bt * N_;
    for (int n0 = 0; n0 < N_; n0 += 64) {
        int nn = (N_ - n0 < 64) ? (N_ - n0) : 64;
        for (int i = t; i < nn * 32; i += 512) {
            int r = i >> 5, c2 = (i & 31) * 2;
            size_t row = (rowbase + n0 + r) * 768;
            *(u32*)&ks[r][c2] = *(const u32*)&qkv[row + 256 + hp * 64 + c2];
            *(u32*)&vs[r][c2] = *(const u32*)&qkv[row + 512 + hp * 64 + c2];
        }
        __syncthreads();
        for (int n = 0; n < nn; ++n) {
            float vv = __bfloat162float(vs[n][hh * 32 + e]);
            #pragma unroll
            for (int r = 0; r < 4; ++r) {
                float kk = __bfloat162float(ks[n][hh * 32 + d0 + 8 * r]);
                acc[r]  += kk * vv;
                ksum[r] += kk;
            }
            vsum += vv;
        }
        __syncthreads();
    }
    __shared__ float km[64];
    __shared__ float vm[64];
    if (e == 0) {
        #pragma unroll
        for (int r = 0; r < 4; ++r) km[hh * 32 + d0 + 8 * r] = ksum[r] * INVN_;
    }
    if (d0 == 0) vm[hh * 32 + e] = vsum * INVN_;
    __syncthreads();
    float vme = vm[hh * 32 + e];
    int bh = bt * 8 + hp * 2 + hh;
    #pragma unroll
    for (int r = 0; r < 4; ++r) {
        int d = d0 + 8 * r;
        float val = acc[r] * (SCALE_ * INVN_) - SCALE_ * km[hh * 32 + d] * vme;
        kv2t[((size_t)bh * 32 + e) * 32 + d] = __float2bfloat16(val);
    }
    if (d0 == 0) vmeanb[bh * 32 + e] = vme;
}

// ---------------------------------------------------------------------------
// fuse_z2: per (bt, 64-row chunk):
//   phase 1 (MFMA): attn[64][256] = q @ kv2t^T + vmean  -> LDS (bf16)
//   phase 2: Z[n][c] = attn[n][c] + rw0*v[n-1][c] + rw1*v[n][c] + rw2*v[n+1][c]
// grid (384, 12), block 256 (4 waves). LDS = 32KB attn + 16KB kv2t = 48KB.
// ---------------------------------------------------------------------------
__global__ __launch_bounds__(256)
void fuse_z2(const __hip_bfloat16* __restrict__ qkv, const __hip_bfloat16* __restrict__ kv2t,
             const float* __restrict__ vmeanb, const float* __restrict__ rw,
             __hip_bfloat16* __restrict__ Z) {
    __shared__ __align__(16) __hip_bfloat16 attn[64][256];
    __shared__ __align__(16) __hip_bfloat16 kvl[8192];
    int bt = blockIdx.x;
    int n0 = blockIdx.y * 64;
    int rows = (N_ - n0 < 64) ? (N_ - n0) : 64;
    int t = threadIdx.x;
    const size_t rowbase = (size_t)bt * N_;

    {
        const __hip_bfloat16* src = kv2t + (size_t)bt * 8192;
        #pragma unroll
        for (int i = 0; i < 4; ++i) {
            int off = (t + i * 256) * 8;
            *(short8*)&kvl[off] = *(const short8*)&src[off];
        }
    }
    __syncthreads();

    {
        int lane = t & 63, wave = t >> 6;
        int l15 = lane & 15, lq = lane >> 4;
        int r0 = wave * 16;
        int gn = n0 + r0 + l15; if (gn > N_ - 1) gn = N_ - 1;
        const __hip_bfloat16* qrow = qkv + (rowbase + gn) * 768;
        #pragma unroll
        for (int h = 0; h < 8; ++h) {
            short8 af = *(const short8*)&qrow[h * 32 + lq * 8];
            #pragma unroll
            for (int half = 0; half < 2; ++half) {
                short8 bf = *(const short8*)&kvl[h * 1024 + (half * 16 + l15) * 32 + lq * 8];
                f32x4 acc = {};
                acc = __builtin_amdgcn_mfma_f32_16x16x32_bf16(af, bf, acc, 0, 0, 0);
                int col = h * 32 + half * 16 + l15;
                float vm = vmeanb[bt * 256 + col];
                #pragma unroll
                for (int j = 0; j < 4; ++j)
                    attn[r0 + lq * 4 + j][col] = __float2bfloat16(acc[j] + vm);
            }
        }
    }
    __syncthreads();

    {
        int c = t;
        float r0w = rw[bt * 768 + c * 3 + 0];
        float r1w = rw[bt * 768 + c * 3 + 1];
        float r2w = rw[bt * 768 + c * 3 + 2];
        const __hip_bfloat16* vb = qkv + rowbase * 768 + 512 + c;
        float vprev = (n0 > 0) ? __bfloat162float(vb[(size_t)(n0 - 1) * 768]) : 0.0f;
        float vcur  = __bfloat162float(vb[(size_t)n0 * 768]);
        #pragma unroll 4
        for (int r = 0; r < rows; ++r) {
            int gn = n0 + r;
            float vnext = (gn + 1 < N_) ? __bfloat162float(vb[(size_t)(gn + 1) * 768]) : 0.0f;
            float s = __bfloat162float(attn[r][c]) + r0w * vprev + r1w * vcur + r2w * vnext;
            Z[(rowbase + gn) * 256 + c] = __float2bfloat16(s);
            vprev = vcur; vcur = vnext;
        }
    }
}

// ---------------------------------------------------------------------------
extern "C" void kernel_launch(void* const* d_in, const int* in_sizes, int n_in,
                              void* d_out, int out_size, void* d_ws, size_t ws_size,
                              hipStream_t stream) {
    (void)in_sizes; (void)n_in; (void)out_size; (void)ws_size;
    const float* x  = (const float*)d_in[0];
    const float* Wq = (const float*)d_in[1];  const float* bq = (const float*)d_in[2];
    const float* Wk = (const float*)d_in[3];  const float* bk = (const float*)d_in[4];
    const float* Wv = (const float*)d_in[5];  const float* bv = (const float*)d_in[6];
    const float* Wo = (const float*)d_in[7];  const float* bo = (const float*)d_in[8];
    const float* w1 = (const float*)d_in[9];  const float* b1 = (const float*)d_in[10];
    const float* w2 = (const float*)d_in[11]; const float* b2 = (const float*)d_in[12];
    float* out = (float*)d_out;

    char* ws = (char*)d_ws;
    size_t off = 0;
    auto take = [&](size_t bytes) -> char* {
        char* p = ws + off;
        off = (off + bytes + 255) & ~(size_t)255;
        return p;
    };

    __hip_bfloat16* qkv   = (__hip_bfloat16*)take((size_t)MROWS * 768 * 2);
    __hip_bfloat16* xb    = (__hip_bfloat16*)take((size_t)MROWS * 256 * 2);
    __hip_bfloat16* Zbuf  = xb;  // alias: xb dead after gemm_qkv, reused for Z
    __hip_bfloat16* wqkv  = (__hip_bfloat16*)take(768 * 256 * 2);
    __hip_bfloat16* wo    = (__hip_bfloat16*)take(256 * 256 * 2);
    float* bqkv   = (float*)take(768 * 4);
    float* msum   = (float*)take(384 * 256 * 4);
    float* rw     = (float*)take(384 * 768 * 4);
    __hip_bfloat16* kv2t = (__hip_bfloat16*)take((size_t)384 * 8192 * 2);
    float* vmeanb = (float*)take(384 * 256 * 4);

    hipMemsetAsync(msum, 0, 384 * 256 * 4, stream);

    prep_weights<<<768, 256, 0, stream>>>(Wq, bq, Wk, bk, Wv, bv, Wo, wqkv, bqkv, wo);
    convert_x<<<dim3(384, 4), 256, 0, stream>>>(x, xb, msum);
    mlp_rw<<<384, 256, 0, stream>>>(msum, w1, b1, w2, b2, rw);
    // QKV projection: [274944,256] x [768,256]^T -> bf16 qkv, bias fused
    gemm_deepk<768, 6, true><<<dim3(6, 2148), 512, 0, stream>>>(xb, wqkv, bqkv, qkv);
    reduce_kv<<<1536, 512, 0, stream>>>(qkv, kv2t, vmeanb);
    fuse_z2<<<dim3(384, 12), 256, 0, stream>>>(qkv, kv2t, vmeanb, rw, Zbuf);
    // Output projection: [274944,256] x [256,256]^T -> f32 out, bias fused
    gemm_deepk<256, 2, false><<<dim3(2, 2148), 512, 0, stream>>>(Zbuf, wo, bo, out);
}

// Round 6
// 762.762 us; speedup vs baseline: 1.2263x; 1.1882x over previous
//
#include <hip/hip_runtime.h>
#include <hip/hip_bf16.h>
#include <math.h>

typedef __attribute__((ext_vector_type(8))) short short8;
typedef __attribute__((ext_vector_type(4))) short sv4;
typedef __attribute__((ext_vector_type(4))) float f32x4;
typedef unsigned int u32;

#define BT_ 384
#define N_ 716
#define C_ 256
#define H_ 8
#define D_ 32
#define MROWS (BT_ * N_)   /* 274944 */
#define SCALE_ 0.17677669529663687f  /* 32^-0.5 */
#define INVN_ (1.0f / 716.0f)

__device__ __forceinline__ void gload_lds16(const void* g, void* l) {
    __builtin_amdgcn_global_load_lds(
        (const __attribute__((address_space(1))) u32*)g,
        (__attribute__((address_space(3))) u32*)l, 16, 0, 0);
}

template<int N>
__device__ __forceinline__ void waitcnt_vm() {
    if constexpr (N == 0)       asm volatile("s_waitcnt vmcnt(0)" ::: "memory");
    else if constexpr (N == 4)  asm volatile("s_waitcnt vmcnt(4)" ::: "memory");
    else if constexpr (N == 8)  asm volatile("s_waitcnt vmcnt(8)" ::: "memory");
    else                        asm volatile("s_waitcnt vmcnt(12)" ::: "memory");
}

// ---------------------------------------------------------------------------
// Assemble bf16 weight matrices + fused qkv bias. Wqkv_b[768][256], Wo_b[256][256]
// ---------------------------------------------------------------------------
__global__ void prep_weights(const float* __restrict__ Wq, const float* __restrict__ bq,
                             const float* __restrict__ Wk, const float* __restrict__ bk,
                             const float* __restrict__ Wv, const float* __restrict__ bv,
                             const float* __restrict__ Wo,
                             __hip_bfloat16* __restrict__ wqkv, float* __restrict__ bqkv,
                             __hip_bfloat16* __restrict__ wo) {
    int idx = blockIdx.x * 256 + threadIdx.x;
    if (idx < 768 * 256) {
        int o = idx >> 8, c = idx & 255;
        const float* W = (o < 256) ? Wq : ((o < 512) ? Wk : Wv);
        int oo = o & 255;
        wqkv[idx] = __float2bfloat16(W[oo * 256 + c]);
    }
    if (idx < 256 * 256) wo[idx] = __float2bfloat16(Wo[idx]);
    if (idx < 768) bqkv[idx] = (idx < 256) ? bq[idx] : ((idx < 512) ? bk[idx - 256] : bv[idx - 512]);
}

// ---------------------------------------------------------------------------
// x fp32 -> bf16 (vectorized float4/short4), plus per-(bt,channel) col sums
// grid (384, 4), block 256.
// ---------------------------------------------------------------------------
__global__ __launch_bounds__(256)
void convert_x(const float* __restrict__ x, __hip_bfloat16* __restrict__ xb,
               float* __restrict__ msum) {
    int bt = blockIdx.x, chunk = blockIdx.y;
    int t = threadIdx.x;
    int c4 = (t & 63) * 4;
    int r0 = t >> 6;
    size_t base = ((size_t)bt * N_ + (size_t)chunk * 179) * C_;
    float s0 = 0.f, s1 = 0.f, s2 = 0.f, s3 = 0.f;
    for (int r = r0; r < 179; r += 4) {
        float4 f = *(const float4*)&x[base + (size_t)r * C_ + c4];
        union { sv4 v; __hip_bfloat16 h[4]; } u;
        u.h[0] = __float2bfloat16(f.x);
        u.h[1] = __float2bfloat16(f.y);
        u.h[2] = __float2bfloat16(f.z);
        u.h[3] = __float2bfloat16(f.w);
        *(sv4*)&xb[base + (size_t)r * C_ + c4] = u.v;
        s0 += f.x; s1 += f.y; s2 += f.z; s3 += f.w;
    }
    atomicAdd(&msum[bt * C_ + c4 + 0], s0);
    atomicAdd(&msum[bt * C_ + c4 + 1], s1);
    atomicAdd(&msum[bt * C_ + c4 + 2], s2);
    atomicAdd(&msum[bt * C_ + c4 + 3], s3);
}

// ---------------------------------------------------------------------------
// Grouped 2-layer MLP -> per-channel 3-tap conv weights rw[bt][768]
// ---------------------------------------------------------------------------
__global__ __launch_bounds__(256)
void mlp_rw(const float* __restrict__ msum, const float* __restrict__ w1,
            const float* __restrict__ b1, const float* __restrict__ w2,
            const float* __restrict__ b2, float* __restrict__ rw) {
    int bt = blockIdx.x;
    int t = threadIdx.x;
    __shared__ float m_l[256];
    __shared__ float h1_l[256];
    m_l[t] = msum[bt * 256 + t] * INVN_;
    __syncthreads();
    int g = t >> 5;
    float a = b1[t];
    #pragma unroll
    for (int i = 0; i < 32; ++i) a += m_l[g * 32 + i] * w1[t * 32 + i];
    h1_l[t] = 0.5f * a * (1.0f + erff(a * 0.70710678118654752f));
    __syncthreads();
    for (int o = t; o < 768; o += 256) {
        int gg = o / 96;
        float s = b2[o];
        #pragma unroll
        for (int i = 0; i < 32; ++i) s += h1_l[gg * 32 + i] * w2[o * 32 + i];
        rw[bt * 768 + o] = s;
    }
}

// ---------------------------------------------------------------------------
// Deep-K bf16 GEMM, B-transposed: out[m][o] = sum_k A[m][k]*Bm[o][k] + bias[o]
// K=256 fully LDS-resident, counted-vmcnt chunk waits (as R5).
// NEW: epilogue stages C through LDS (padded stride) and writes coalesced
// vectorized 16-B stores instead of scalar 2-B/4-B scattered stores.
// grid (GRIDX, 2148), block 512.
// ---------------------------------------------------------------------------
template<int NCOLS, int GRIDX, bool OUT_BF16>
__global__ __launch_bounds__(512, 1)
void gemm_deepk(const __hip_bfloat16* __restrict__ A, const __hip_bfloat16* __restrict__ Bm,
                const float* __restrict__ bias, void* __restrict__ outp) {
    __shared__ __align__(16) char smem[131072];
    __hip_bfloat16* Asb = (__hip_bfloat16*)smem;             // [4][128*64]
    __hip_bfloat16* Bsb = (__hip_bfloat16*)(smem + 65536);   // [4][128*64]

    constexpr int NWG = GRIDX * (MROWS / 128);
    constexpr int PER = NWG / 8;
    const int lin = blockIdx.y * GRIDX + blockIdx.x;
    const int tt  = (lin & 7) * PER + (lin >> 3);
    const int bx = tt % GRIDX, by = tt / GRIDX;

    const int tid  = threadIdx.x;
    const int lane = tid & 63;
    const int wave = tid >> 6;           // 0..7
    const int wr = wave & 1;             // row half (64 rows)
    const int wc = wave >> 1;            // col quarter (32 cols)
    const int l15 = lane & 15, lq = lane >> 4;
    const size_t rowBase = (size_t)by * 128;
    const int    colBase = bx * 128;
    const int lrow = lane >> 3;                 // 0..7
    const int gsl  = ((lane & 7) ^ lrow) * 8;   // XOR-swizzled source slot

    // ---- one-shot staging: 16 loads per wave, issued in K-chunk order ----
    const __hip_bfloat16* Ab = A  + (rowBase + wave * 16 + lrow) * 256 + gsl;
    const __hip_bfloat16* Bb = Bm + (size_t)(colBase + wave * 16 + lrow) * 256 + gsl;
    #pragma unroll
    for (int ks = 0; ks < 4; ++ks) {
        #pragma unroll
        for (int i = 0; i < 2; ++i)
            gload_lds16(Ab + (size_t)i * 8 * 256 + ks * 64, &Asb[ks * 8192 + (wave * 16 + i * 8) * 64]);
        #pragma unroll
        for (int i = 0; i < 2; ++i)
            gload_lds16(Bb + (size_t)i * 8 * 256 + ks * 64, &Bsb[ks * 8192 + (wave * 16 + i * 8) * 64]);
    }

    f32x4 acc[4][2] = {};

    #pragma unroll
    for (int ks = 0; ks < 4; ++ks) {
        if (ks == 0) waitcnt_vm<12>();
        else if (ks == 1) waitcnt_vm<8>();
        else if (ks == 2) waitcnt_vm<4>();
        else waitcnt_vm<0>();
        __builtin_amdgcn_s_barrier();
        __builtin_amdgcn_sched_barrier(0);
        #pragma unroll
        for (int kk = 0; kk < 64; kk += 32) {
            const int sb = (kk >> 3) + lq;
            const int sl = ((sb ^ (l15 & 7)) * 8);
            short8 af[4], bf[2];
            #pragma unroll
            for (int m = 0; m < 4; ++m)
                af[m] = *(const short8*)&Asb[ks * 8192 + (wr * 64 + m * 16 + l15) * 64 + sl];
            #pragma unroll
            for (int n = 0; n < 2; ++n)
                bf[n] = *(const short8*)&Bsb[ks * 8192 + (wc * 32 + n * 16 + l15) * 64 + sl];
            #pragma unroll
            for (int m = 0; m < 4; ++m)
                #pragma unroll
                for (int n = 0; n < 2; ++n)
                    acc[m][n] = __builtin_amdgcn_mfma_f32_16x16x32_bf16(af[m], bf[n], acc[m][n], 0, 0, 0);
        }
    }

    // ---- epilogue: stage C in LDS (padded), then coalesced vector stores ----
    __syncthreads();   // staging LDS dead after this

    if constexpr (OUT_BF16) {
        __hip_bfloat16* Cs = (__hip_bfloat16*)smem;     // [128][136], 34 KB
        #pragma unroll
        for (int n = 0; n < 2; ++n) {
            int col = wc * 32 + n * 16 + l15;
            float bv = bias[colBase + col];
            #pragma unroll
            for (int m = 0; m < 4; ++m) {
                int row0 = wr * 64 + m * 16 + lq * 4;
                #pragma unroll
                for (int j = 0; j < 4; ++j)
                    Cs[(row0 + j) * 136 + col] = __float2bfloat16(acc[m][n][j] + bv);
            }
        }
        __syncthreads();
        int row = tid >> 2, cq = tid & 3;
        __hip_bfloat16* og = (__hip_bfloat16*)outp + (rowBase + row) * NCOLS + colBase;
        #pragma unroll
        for (int i = 0; i < 4; ++i) {
            int col = cq * 8 + i * 32;
            *(short8*)&og[col] = *(const short8*)&Cs[row * 136 + col];
        }
    } else {
        float* Cs = (float*)smem;                        // [128][132], 67.5 KB
        #pragma unroll
        for (int n = 0; n < 2; ++n) {
            int col = wc * 32 + n * 16 + l15;
            float bv = bias[colBase + col];
            #pragma unroll
            for (int m = 0; m < 4; ++m) {
                int row0 = wr * 64 + m * 16 + lq * 4;
                #pragma unroll
                for (int j = 0; j < 4; ++j)
                    Cs[(row0 + j) * 132 + col] = acc[m][n][j] + bv;
            }
        }
        __syncthreads();
        int row = tid >> 2, cq = tid & 3;
        float* og = (float*)outp + (rowBase + row) * NCOLS + colBase;
        #pragma unroll
        for (int i = 0; i < 8; ++i) {
            int col = cq * 4 + i * 16;
            *(float4*)&og[col] = *(const float4*)&Cs[row * 132 + col];
        }
    }
}

// ---------------------------------------------------------------------------
// Per-(bt, head-pair): kv2t[bh][e][d] (bf16) and vmean. 512 threads cover two
// adjacent heads (full 128B cache lines on k/v reads). grid 1536 = bt*4 + hp.
// ---------------------------------------------------------------------------
__global__ __launch_bounds__(512)
void reduce_kv(const __hip_bfloat16* __restrict__ qkv, __hip_bfloat16* __restrict__ kv2t,
               float* __restrict__ vmeanb) {
    int blk = blockIdx.x;
    int bt = blk >> 2, hp = blk & 3;          // head pair: heads 2hp, 2hp+1
    int t = threadIdx.x;
    int hh = t >> 8;                          // 0/1 within pair
    int ti = t & 255;
    int e = ti & 31, d0 = ti >> 5;
    __shared__ __hip_bfloat16 ks[64][64];
    __shared__ __hip_bfloat16 vs[64][64];
    float acc[4] = {0.f, 0.f, 0.f, 0.f};
    float ksum[4] = {0.f, 0.f, 0.f, 0.f};
    float vsum = 0.f;
    const size_t rowbase = (size_t)bt * N_;
    for (int n0 = 0; n0 < N_; n0 += 64) {
        int nn = (N_ - n0 < 64) ? (N_ - n0) : 64;
        for (int i = t; i < nn * 32; i += 512) {
            int r = i >> 5, c2 = (i & 31) * 2;
            size_t row = (rowbase + n0 + r) * 768;
            *(u32*)&ks[r][c2] = *(const u32*)&qkv[row + 256 + hp * 64 + c2];
            *(u32*)&vs[r][c2] = *(const u32*)&qkv[row + 512 + hp * 64 + c2];
        }
        __syncthreads();
        for (int n = 0; n < nn; ++n) {
            float vv = __bfloat162float(vs[n][hh * 32 + e]);
            #pragma unroll
            for (int r = 0; r < 4; ++r) {
                float kk = __bfloat162float(ks[n][hh * 32 + d0 + 8 * r]);
                acc[r]  += kk * vv;
                ksum[r] += kk;
            }
            vsum += vv;
        }
        __syncthreads();
    }
    __shared__ float km[64];
    __shared__ float vm[64];
    if (e == 0) {
        #pragma unroll
        for (int r = 0; r < 4; ++r) km[hh * 32 + d0 + 8 * r] = ksum[r] * INVN_;
    }
    if (d0 == 0) vm[hh * 32 + e] = vsum * INVN_;
    __syncthreads();
    float vme = vm[hh * 32 + e];
    int bh = bt * 8 + hp * 2 + hh;
    #pragma unroll
    for (int r = 0; r < 4; ++r) {
        int d = d0 + 8 * r;
        float val = acc[r] * (SCALE_ * INVN_) - SCALE_ * km[hh * 32 + d] * vme;
        kv2t[((size_t)bh * 32 + e) * 32 + d] = __float2bfloat16(val);
    }
    if (d0 == 0) vmeanb[bh * 32 + e] = vme;
}

// ---------------------------------------------------------------------------
// fuse_z2: per (bt, 64-row chunk):
//   phase 1 (MFMA): attn[64][256] = q @ kv2t^T + vmean  -> LDS (bf16)
//   phase 2 (vectorized): 8 channels/thread, short8 loads/stores, taps in regs
// grid (384, 12), block 256 (4 waves). LDS = 32KB attn + 16KB kv2t = 48KB.
// ---------------------------------------------------------------------------
__global__ __launch_bounds__(256)
void fuse_z2(const __hip_bfloat16* __restrict__ qkv, const __hip_bfloat16* __restrict__ kv2t,
             const float* __restrict__ vmeanb, const float* __restrict__ rw,
             __hip_bfloat16* __restrict__ Z) {
    __shared__ __align__(16) __hip_bfloat16 attn[64][256];
    __shared__ __align__(16) __hip_bfloat16 kvl[8192];
    int bt = blockIdx.x;
    int n0 = blockIdx.y * 64;
    int rows = (N_ - n0 < 64) ? (N_ - n0) : 64;
    int t = threadIdx.x;
    const size_t rowbase = (size_t)bt * N_;

    {
        const __hip_bfloat16* src = kv2t + (size_t)bt * 8192;
        #pragma unroll
        for (int i = 0; i < 4; ++i) {
            int off = (t + i * 256) * 8;
            *(short8*)&kvl[off] = *(const short8*)&src[off];
        }
    }
    __syncthreads();

    {
        int lane = t & 63, wave = t >> 6;
        int l15 = lane & 15, lq = lane >> 4;
        int r0 = wave * 16;
        int gn = n0 + r0 + l15; if (gn > N_ - 1) gn = N_ - 1;
        const __hip_bfloat16* qrow = qkv + (rowbase + gn) * 768;
        #pragma unroll
        for (int h = 0; h < 8; ++h) {
            short8 af = *(const short8*)&qrow[h * 32 + lq * 8];
            #pragma unroll
            for (int half = 0; half < 2; ++half) {
                short8 bf = *(const short8*)&kvl[h * 1024 + (half * 16 + l15) * 32 + lq * 8];
                f32x4 acc = {};
                acc = __builtin_amdgcn_mfma_f32_16x16x32_bf16(af, bf, acc, 0, 0, 0);
                int col = h * 32 + half * 16 + l15;
                float vm = vmeanb[bt * 256 + col];
                #pragma unroll
                for (int j = 0; j < 4; ++j)
                    attn[r0 + lq * 4 + j][col] = __float2bfloat16(acc[j] + vm);
            }
        }
    }
    __syncthreads();

    {
        int tr = t >> 5;            // 0..7 row sub-range
        int c8 = (t & 31) * 8;      // channel base
        float w0[8], w1_[8], w2_[8];
        #pragma unroll
        for (int u = 0; u < 8; ++u) {
            w0[u]  = rw[bt * 768 + (c8 + u) * 3 + 0];
            w1_[u] = rw[bt * 768 + (c8 + u) * 3 + 1];
            w2_[u] = rw[bt * 768 + (c8 + u) * 3 + 2];
        }
        int rbeg = tr * 8;
        if (rbeg < rows) {
            int rend = rbeg + 8; if (rend > rows) rend = rows;
            union U8 { short8 v; __hip_bfloat16 h[8]; };
            auto loadv = [&](int gn, float* dst) {
                if (gn >= 0 && gn < N_) {
                    U8 u; u.v = *(const short8*)&qkv[(rowbase + gn) * 768 + 512 + c8];
                    #pragma unroll
                    for (int uu = 0; uu < 8; ++uu) dst[uu] = __bfloat162float(u.h[uu]);
                } else {
                    #pragma unroll
                    for (int uu = 0; uu < 8; ++uu) dst[uu] = 0.0f;
                }
            };
            float vprev[8], vcur[8], vnext[8];
            loadv(n0 + rbeg - 1, vprev);
            loadv(n0 + rbeg, vcur);
            for (int r = rbeg; r < rend; ++r) {
                int gn = n0 + r;
                loadv(gn + 1, vnext);
                U8 at; at.v = *(const short8*)&attn[r][c8];
                U8 zv;
                #pragma unroll
                for (int u = 0; u < 8; ++u) {
                    float s = __bfloat162float(at.h[u]) + w0[u] * vprev[u]
                              + w1_[u] * vcur[u] + w2_[u] * vnext[u];
                    zv.h[u] = __float2bfloat16(s);
                }
                *(short8*)&Z[(rowbase + gn) * 256 + c8] = zv.v;
                #pragma unroll
                for (int u = 0; u < 8; ++u) { vprev[u] = vcur[u]; vcur[u] = vnext[u]; }
            }
        }
    }
}

// ---------------------------------------------------------------------------
extern "C" void kernel_launch(void* const* d_in, const int* in_sizes, int n_in,
                              void* d_out, int out_size, void* d_ws, size_t ws_size,
                              hipStream_t stream) {
    (void)in_sizes; (void)n_in; (void)out_size; (void)ws_size;
    const float* x  = (const float*)d_in[0];
    const float* Wq = (const float*)d_in[1];  const float* bq = (const float*)d_in[2];
    const float* Wk = (const float*)d_in[3];  const float* bk = (const float*)d_in[4];
    const float* Wv = (const float*)d_in[5];  const float* bv = (const float*)d_in[6];
    const float* Wo = (const float*)d_in[7];  const float* bo = (const float*)d_in[8];
    const float* w1 = (const float*)d_in[9];  const float* b1 = (const float*)d_in[10];
    const float* w2 = (const float*)d_in[11]; const float* b2 = (const float*)d_in[12];
    float* out = (float*)d_out;

    char* ws = (char*)d_ws;
    size_t off = 0;
    auto take = [&](size_t bytes) -> char* {
        char* p = ws + off;
        off = (off + bytes + 255) & ~(size_t)255;
        return p;
    };

    __hip_bfloat16* qkv   = (__hip_bfloat16*)take((size_t)MROWS * 768 * 2);
    __hip_bfloat16* xb    = (__hip_bfloat16*)take((size_t)MROWS * 256 * 2);
    __hip_bfloat16* Zbuf  = xb;  // alias: xb dead after gemm_qkv, reused for Z
    __hip_bfloat16* wqkv  = (__hip_bfloat16*)take(768 * 256 * 2);
    __hip_bfloat16* wo    = (__hip_bfloat16*)take(256 * 256 * 2);
    float* bqkv   = (float*)take(768 * 4);
    float* msum   = (float*)take(384 * 256 * 4);
    float* rw     = (float*)take(384 * 768 * 4);
    __hip_bfloat16* kv2t = (__hip_bfloat16*)take((size_t)384 * 8192 * 2);
    float* vmeanb = (float*)take(384 * 256 * 4);

    hipMemsetAsync(msum, 0, 384 * 256 * 4, stream);

    prep_weights<<<768, 256, 0, stream>>>(Wq, bq, Wk, bk, Wv, bv, Wo, wqkv, bqkv, wo);
    convert_x<<<dim3(384, 4), 256, 0, stream>>>(x, xb, msum);
    mlp_rw<<<384, 256, 0, stream>>>(msum, w1, b1, w2, b2, rw);
    // QKV projection: [274944,256] x [768,256]^T -> bf16 qkv, bias fused
    gemm_deepk<768, 6, true><<<dim3(6, 2148), 512, 0, stream>>>(xb, wqkv, bqkv, qkv);
    reduce_kv<<<1536, 512, 0, stream>>>(qkv, kv2t, vmeanb);
    fuse_z2<<<dim3(384, 12), 256, 0, stream>>>(qkv, kv2t, vmeanb, rw, Zbuf);
    // Output projection: [274944,256] x [256,256]^T -> f32 out, bias fused
    gemm_deepk<256, 2, false><<<dim3(2, 2148), 512, 0, stream>>>(Zbuf, wo, bo, out);
}

// Round 7
// 703.179 us; speedup vs baseline: 1.3302x; 1.0847x over previous
//
#include <hip/hip_runtime.h>
#include <hip/hip_bf16.h>
#include <math.h>

typedef __attribute__((ext_vector_type(8))) short short8;
typedef __attribute__((ext_vector_type(4))) short sv4;
typedef __attribute__((ext_vector_type(4))) float f32x4;
typedef unsigned int u32;

#define BT_ 384
#define N_ 716
#define C_ 256
#define H_ 8
#define D_ 32
#define MROWS (BT_ * N_)   /* 274944 */
#define SCALE_ 0.17677669529663687f  /* 32^-0.5 */
#define INVN_ (1.0f / 716.0f)

__device__ __forceinline__ void gload_lds16(const void* g, void* l) {
    __builtin_amdgcn_global_load_lds(
        (const __attribute__((address_space(1))) u32*)g,
        (__attribute__((address_space(3))) u32*)l, 16, 0, 0);
}

// ---------------------------------------------------------------------------
// Assemble bf16 weight matrices + fused qkv bias. Wqkv_b[768][256], Wo_b[256][256]
// ---------------------------------------------------------------------------
__global__ void prep_weights(const float* __restrict__ Wq, const float* __restrict__ bq,
                             const float* __restrict__ Wk, const float* __restrict__ bk,
                             const float* __restrict__ Wv, const float* __restrict__ bv,
                             const float* __restrict__ Wo,
                             __hip_bfloat16* __restrict__ wqkv, float* __restrict__ bqkv,
                             __hip_bfloat16* __restrict__ wo) {
    int idx = blockIdx.x * 256 + threadIdx.x;
    if (idx < 768 * 256) {
        int o = idx >> 8, c = idx & 255;
        const float* W = (o < 256) ? Wq : ((o < 512) ? Wk : Wv);
        int oo = o & 255;
        wqkv[idx] = __float2bfloat16(W[oo * 256 + c]);
    }
    if (idx < 256 * 256) wo[idx] = __float2bfloat16(Wo[idx]);
    if (idx < 768) bqkv[idx] = (idx < 256) ? bq[idx] : ((idx < 512) ? bk[idx - 256] : bv[idx - 512]);
}

// ---------------------------------------------------------------------------
// x fp32 -> bf16 (vectorized float4/short4), plus per-(bt,channel) col sums
// grid (384, 4), block 256.
// ---------------------------------------------------------------------------
__global__ __launch_bounds__(256)
void convert_x(const float* __restrict__ x, __hip_bfloat16* __restrict__ xb,
               float* __restrict__ msum) {
    int bt = blockIdx.x, chunk = blockIdx.y;
    int t = threadIdx.x;
    int c4 = (t & 63) * 4;
    int r0 = t >> 6;
    size_t base = ((size_t)bt * N_ + (size_t)chunk * 179) * C_;
    float s0 = 0.f, s1 = 0.f, s2 = 0.f, s3 = 0.f;
    for (int r = r0; r < 179; r += 4) {
        float4 f = *(const float4*)&x[base + (size_t)r * C_ + c4];
        union { sv4 v; __hip_bfloat16 h[4]; } u;
        u.h[0] = __float2bfloat16(f.x);
        u.h[1] = __float2bfloat16(f.y);
        u.h[2] = __float2bfloat16(f.z);
        u.h[3] = __float2bfloat16(f.w);
        *(sv4*)&xb[base + (size_t)r * C_ + c4] = u.v;
        s0 += f.x; s1 += f.y; s2 += f.z; s3 += f.w;
    }
    atomicAdd(&msum[bt * C_ + c4 + 0], s0);
    atomicAdd(&msum[bt * C_ + c4 + 1], s1);
    atomicAdd(&msum[bt * C_ + c4 + 2], s2);
    atomicAdd(&msum[bt * C_ + c4 + 3], s3);
}

// ---------------------------------------------------------------------------
// Grouped 2-layer MLP -> per-channel 3-tap conv weights rw[bt][768]
// ---------------------------------------------------------------------------
__global__ __launch_bounds__(256)
void mlp_rw(const float* __restrict__ msum, const float* __restrict__ w1,
            const float* __restrict__ b1, const float* __restrict__ w2,
            const float* __restrict__ b2, float* __restrict__ rw) {
    int bt = blockIdx.x;
    int t = threadIdx.x;
    __shared__ float m_l[256];
    __shared__ float h1_l[256];
    m_l[t] = msum[bt * 256 + t] * INVN_;
    __syncthreads();
    int g = t >> 5;
    float a = b1[t];
    #pragma unroll
    for (int i = 0; i < 32; ++i) a += m_l[g * 32 + i] * w1[t * 32 + i];
    h1_l[t] = 0.5f * a * (1.0f + erff(a * 0.70710678118654752f));
    __syncthreads();
    for (int o = t; o < 768; o += 256) {
        int gg = o / 96;
        float s = b2[o];
        #pragma unroll
        for (int i = 0; i < 32; ++i) s += h1_l[gg * 32 + i] * w2[o * 32 + i];
        rw[bt * 768 + o] = s;
    }
}

// ---------------------------------------------------------------------------
// Persistent B-resident GEMM: out[m][o] = sum_k A[m][k]*Bm[o][k] + bias[o]
// K=256. Block = (col-tile cb of 128, stripe ib of 256): grid-strides over
// row-tiles rt = ib, ib+256, ... (BM=64). B fragments held in REGISTERS
// (loaded once, L2-hot weight matrix). A double-buffered in 64KB LDS with
// XOR swizzle (pre-swizzled global source). 4 waves, wave tile 32x64.
// Pipeline per tile: stage(next) -> compute(cur) -> [lgkm0+bar] -> C->LDS
// -> [lgkm0+bar] -> coalesced store -> [vmcnt(4)+lgkm0+bar].
// grid (NCOLS/128, 256), block 256.
// ---------------------------------------------------------------------------
template<int NCOLS, bool OUT_BF16>
__global__ __launch_bounds__(256, 2)
void gemm_persist(const __hip_bfloat16* __restrict__ A, const __hip_bfloat16* __restrict__ Bm,
                  const float* __restrict__ bias, void* __restrict__ outp) {
    __shared__ __align__(16) __hip_bfloat16 As[2][64 * 256];   // 2 x 32KB
    constexpr int NT = MROWS / 64;   // 4296 row-tiles
    const int cb = blockIdx.x;
    const int ib = blockIdx.y;       // 0..255
    const int tid = threadIdx.x;
    const int lane = tid & 63;
    const int wave = tid >> 6;       // 0..3
    const int wm = wave & 1;         // row half (32 rows)
    const int wn = wave >> 1;        // col half (64 cols)
    const int colBase = cb * 128;
    const int l15 = lane & 15, lq = lane >> 4;
    const int lrow2 = lane >> 5;     // 0/1 (row within staged pair)
    const int p = lane & 31;         // 16B slot position within 512B row

    // ---- stage one 64x256 A tile into As[buf] (8 gload_lds16 per wave) ----
    auto stageA = [&](int rt, int buf) {
        #pragma unroll
        for (int i = 0; i < 8; ++i) {
            int r = wave * 16 + 2 * i + lrow2;   // row within tile (per-lane)
            const __hip_bfloat16* g = A + ((size_t)rt * 64 + r) * 256 + ((p ^ (r & 7)) * 8);
            gload_lds16(g, &As[buf][(wave * 16 + 2 * i) * 256]);
        }
    };

    stageA(ib, 0);

    // ---- B fragments in registers (loop-invariant; weights are L2-hot) ----
    short8 bf[4][8];
    #pragma unroll
    for (int n = 0; n < 4; ++n)
        #pragma unroll
        for (int ks = 0; ks < 8; ++ks)
            bf[n][ks] = *(const short8*)&Bm[(size_t)(colBase + wn * 64 + n * 16 + l15) * 256 + ks * 32 + lq * 8];
    float biasr[4];
    #pragma unroll
    for (int n = 0; n < 4; ++n)
        biasr[n] = bias[colBase + wn * 64 + n * 16 + l15];

    asm volatile("s_waitcnt vmcnt(0)" ::: "memory");
    __builtin_amdgcn_s_barrier();

    int buf = 0;
    for (int rt = ib; rt < NT; rt += 256) {
        int rtn = rt + 256;
        if (rtn < NT) stageA(rtn, buf ^ 1);

        // ---- compute 64x128 tile: A from LDS (swizzled), B from regs ----
        f32x4 acc[2][4] = {};
        #pragma unroll
        for (int ks = 0; ks < 8; ++ks) {
            short8 af[2];
            #pragma unroll
            for (int m = 0; m < 2; ++m) {
                int row = wm * 32 + m * 16 + l15;
                af[m] = *(const short8*)&As[buf][row * 256 + (((ks * 4 + lq) ^ (row & 7)) * 8)];
            }
            #pragma unroll
            for (int m = 0; m < 2; ++m)
                #pragma unroll
                for (int n = 0; n < 4; ++n)
                    acc[m][n] = __builtin_amdgcn_mfma_f32_16x16x32_bf16(af[m], bf[n][ks], acc[m][n], 0, 0, 0);
        }
        asm volatile("s_waitcnt lgkmcnt(0)" ::: "memory");
        __builtin_amdgcn_s_barrier();          // all waves done reading As[buf]

        // ---- C -> LDS (reuse dead As[buf]), then coalesced store ----
        if constexpr (OUT_BF16) {
            __hip_bfloat16* Cs = &As[buf][0];  // [64][136] padded
            #pragma unroll
            for (int m = 0; m < 2; ++m)
                #pragma unroll
                for (int n = 0; n < 4; ++n) {
                    int col = wn * 64 + n * 16 + l15;
                    #pragma unroll
                    for (int j = 0; j < 4; ++j)
                        Cs[(wm * 32 + m * 16 + lq * 4 + j) * 136 + col] =
                            __float2bfloat16(acc[m][n][j] + biasr[n]);
                }
            asm volatile("s_waitcnt lgkmcnt(0)" ::: "memory");
            __builtin_amdgcn_s_barrier();
            int row = tid >> 2, cq = tid & 3;
            __hip_bfloat16* og = (__hip_bfloat16*)outp + ((size_t)rt * 64 + row) * NCOLS + colBase;
            #pragma unroll
            for (int i = 0; i < 4; ++i) {
                int col = cq * 8 + i * 32;
                *(short8*)&og[col] = *(const short8*)&Cs[row * 136 + col];
            }
        } else {
            float* Cs = (float*)&As[buf][0];   // [64][128] exact 32KB
            #pragma unroll
            for (int m = 0; m < 2; ++m)
                #pragma unroll
                for (int n = 0; n < 4; ++n) {
                    int col = wn * 64 + n * 16 + l15;
                    #pragma unroll
                    for (int j = 0; j < 4; ++j)
                        Cs[(wm * 32 + m * 16 + lq * 4 + j) * 128 + col] = acc[m][n][j] + biasr[n];
                }
            asm volatile("s_waitcnt lgkmcnt(0)" ::: "memory");
            __builtin_amdgcn_s_barrier();
            int row = tid >> 2, cq = tid & 3;
            float* og = (float*)outp + ((size_t)rt * 64 + row) * NCOLS + colBase;
            #pragma unroll
            for (int i = 0; i < 8; ++i) {
                int col = cq * 4 + i * 16;
                *(float4*)&og[col] = *(const float4*)&Cs[row * 128 + col];
            }
        }
        // stage loads (oldest) must land; this iter's stores may stay in flight
        asm volatile("s_waitcnt vmcnt(4) lgkmcnt(0)" ::: "memory");
        __builtin_amdgcn_s_barrier();
        buf ^= 1;
    }
}

// ---------------------------------------------------------------------------
// Per-(bt, head-pair): kv2t[bh][e][d] (bf16) and vmean. 512 threads cover two
// adjacent heads (full 128B cache lines on k/v reads). grid 1536 = bt*4 + hp.
// ---------------------------------------------------------------------------
__global__ __launch_bounds__(512)
void reduce_kv(const __hip_bfloat16* __restrict__ qkv, __hip_bfloat16* __restrict__ kv2t,
               float* __restrict__ vmeanb) {
    int blk = blockIdx.x;
    int bt = blk >> 2, hp = blk & 3;          // head pair: heads 2hp, 2hp+1
    int t = threadIdx.x;
    int hh = t >> 8;                          // 0/1 within pair
    int ti = t & 255;
    int e = ti & 31, d0 = ti >> 5;
    __shared__ __hip_bfloat16 ks[64][64];
    __shared__ __hip_bfloat16 vs[64][64];
    float acc[4] = {0.f, 0.f, 0.f, 0.f};
    float ksum[4] = {0.f, 0.f, 0.f, 0.f};
    float vsum = 0.f;
    const size_t rowbase = (size_t)bt * N_;
    for (int n0 = 0; n0 < N_; n0 += 64) {
        int nn = (N_ - n0 < 64) ? (N_ - n0) : 64;
        for (int i = t; i < nn * 32; i += 512) {
            int r = i >> 5, c2 = (i & 31) * 2;
            size_t row = (rowbase + n0 + r) * 768;
            *(u32*)&ks[r][c2] = *(const u32*)&qkv[row + 256 + hp * 64 + c2];
            *(u32*)&vs[r][c2] = *(const u32*)&qkv[row + 512 + hp * 64 + c2];
        }
        __syncthreads();
        for (int n = 0; n < nn; ++n) {
            float vv = __bfloat162float(vs[n][hh * 32 + e]);
            #pragma unroll
            for (int r = 0; r < 4; ++r) {
                float kk = __bfloat162float(ks[n][hh * 32 + d0 + 8 * r]);
                acc[r]  += kk * vv;
                ksum[r] += kk;
            }
            vsum += vv;
        }
        __syncthreads();
    }
    __shared__ float km[64];
    __shared__ float vm[64];
    if (e == 0) {
        #pragma unroll
        for (int r = 0; r < 4; ++r) km[hh * 32 + d0 + 8 * r] = ksum[r] * INVN_;
    }
    if (d0 == 0) vm[hh * 32 + e] = vsum * INVN_;
    __syncthreads();
    float vme = vm[hh * 32 + e];
    int bh = bt * 8 + hp * 2 + hh;
    #pragma unroll
    for (int r = 0; r < 4; ++r) {
        int d = d0 + 8 * r;
        float val = acc[r] * (SCALE_ * INVN_) - SCALE_ * km[hh * 32 + d] * vme;
        kv2t[((size_t)bh * 32 + e) * 32 + d] = __float2bfloat16(val);
    }
    if (d0 == 0) vmeanb[bh * 32 + e] = vme;
}

// ---------------------------------------------------------------------------
// fuse_z2: per (bt, 64-row chunk):
//   phase 1 (MFMA): attn[64][256] = q @ kv2t^T + vmean  -> LDS (bf16)
//   phase 2 (vectorized): 8 channels/thread, short8 loads/stores, taps in regs
// grid (384, 12), block 256 (4 waves). LDS = 32KB attn + 16KB kv2t = 48KB.
// ---------------------------------------------------------------------------
__global__ __launch_bounds__(256)
void fuse_z2(const __hip_bfloat16* __restrict__ qkv, const __hip_bfloat16* __restrict__ kv2t,
             const float* __restrict__ vmeanb, const float* __restrict__ rw,
             __hip_bfloat16* __restrict__ Z) {
    __shared__ __align__(16) __hip_bfloat16 attn[64][256];
    __shared__ __align__(16) __hip_bfloat16 kvl[8192];
    int bt = blockIdx.x;
    int n0 = blockIdx.y * 64;
    int rows = (N_ - n0 < 64) ? (N_ - n0) : 64;
    int t = threadIdx.x;
    const size_t rowbase = (size_t)bt * N_;

    {
        const __hip_bfloat16* src = kv2t + (size_t)bt * 8192;
        #pragma unroll
        for (int i = 0; i < 4; ++i) {
            int off = (t + i * 256) * 8;
            *(short8*)&kvl[off] = *(const short8*)&src[off];
        }
    }
    __syncthreads();

    {
        int lane = t & 63, wave = t >> 6;
        int l15 = lane & 15, lq = lane >> 4;
        int r0 = wave * 16;
        int gn = n0 + r0 + l15; if (gn > N_ - 1) gn = N_ - 1;
        const __hip_bfloat16* qrow = qkv + (rowbase + gn) * 768;
        #pragma unroll
        for (int h = 0; h < 8; ++h) {
            short8 af = *(const short8*)&qrow[h * 32 + lq * 8];
            #pragma unroll
            for (int half = 0; half < 2; ++half) {
                short8 bfr = *(const short8*)&kvl[h * 1024 + (half * 16 + l15) * 32 + lq * 8];
                f32x4 acc = {};
                acc = __builtin_amdgcn_mfma_f32_16x16x32_bf16(af, bfr, acc, 0, 0, 0);
                int col = h * 32 + half * 16 + l15;
                float vm = vmeanb[bt * 256 + col];
                #pragma unroll
                for (int j = 0; j < 4; ++j)
                    attn[r0 + lq * 4 + j][col] = __float2bfloat16(acc[j] + vm);
            }
        }
    }
    __syncthreads();

    {
        int tr = t >> 5;            // 0..7 row sub-range
        int c8 = (t & 31) * 8;      // channel base
        float w0[8], w1_[8], w2_[8];
        #pragma unroll
        for (int u = 0; u < 8; ++u) {
            w0[u]  = rw[bt * 768 + (c8 + u) * 3 + 0];
            w1_[u] = rw[bt * 768 + (c8 + u) * 3 + 1];
            w2_[u] = rw[bt * 768 + (c8 + u) * 3 + 2];
        }
        int rbeg = tr * 8;
        if (rbeg < rows) {
            int rend = rbeg + 8; if (rend > rows) rend = rows;
            union U8 { short8 v; __hip_bfloat16 h[8]; };
            auto loadv = [&](int gn, float* dst) {
                if (gn >= 0 && gn < N_) {
                    U8 u; u.v = *(const short8*)&qkv[(rowbase + gn) * 768 + 512 + c8];
                    #pragma unroll
                    for (int uu = 0; uu < 8; ++uu) dst[uu] = __bfloat162float(u.h[uu]);
                } else {
                    #pragma unroll
                    for (int uu = 0; uu < 8; ++uu) dst[uu] = 0.0f;
                }
            };
            float vprev[8], vcur[8], vnext[8];
            loadv(n0 + rbeg - 1, vprev);
            loadv(n0 + rbeg, vcur);
            for (int r = rbeg; r < rend; ++r) {
                int gn = n0 + r;
                loadv(gn + 1, vnext);
                U8 at; at.v = *(const short8*)&attn[r][c8];
                U8 zv;
                #pragma unroll
                for (int u = 0; u < 8; ++u) {
                    float s = __bfloat162float(at.h[u]) + w0[u] * vprev[u]
                              + w1_[u] * vcur[u] + w2_[u] * vnext[u];
                    zv.h[u] = __float2bfloat16(s);
                }
                *(short8*)&Z[(rowbase + gn) * 256 + c8] = zv.v;
                #pragma unroll
                for (int u = 0; u < 8; ++u) { vprev[u] = vcur[u]; vcur[u] = vnext[u]; }
            }
        }
    }
}

// ---------------------------------------------------------------------------
extern "C" void kernel_launch(void* const* d_in, const int* in_sizes, int n_in,
                              void* d_out, int out_size, void* d_ws, size_t ws_size,
                              hipStream_t stream) {
    (void)in_sizes; (void)n_in; (void)out_size; (void)ws_size;
    const float* x  = (const float*)d_in[0];
    const float* Wq = (const float*)d_in[1];  const float* bq = (const float*)d_in[2];
    const float* Wk = (const float*)d_in[3];  const float* bk = (const float*)d_in[4];
    const float* Wv = (const float*)d_in[5];  const float* bv = (const float*)d_in[6];
    const float* Wo = (const float*)d_in[7];  const float* bo = (const float*)d_in[8];
    const float* w1 = (const float*)d_in[9];  const float* b1 = (const float*)d_in[10];
    const float* w2 = (const float*)d_in[11]; const float* b2 = (const float*)d_in[12];
    float* out = (float*)d_out;

    char* ws = (char*)d_ws;
    size_t off = 0;
    auto take = [&](size_t bytes) -> char* {
        char* p = ws + off;
        off = (off + bytes + 255) & ~(size_t)255;
        return p;
    };

    __hip_bfloat16* qkv   = (__hip_bfloat16*)take((size_t)MROWS * 768 * 2);
    __hip_bfloat16* xb    = (__hip_bfloat16*)take((size_t)MROWS * 256 * 2);
    __hip_bfloat16* Zbuf  = xb;  // alias: xb dead after gemm_qkv, reused for Z
    __hip_bfloat16* wqkv  = (__hip_bfloat16*)take(768 * 256 * 2);
    __hip_bfloat16* wo    = (__hip_bfloat16*)take(256 * 256 * 2);
    float* bqkv   = (float*)take(768 * 4);
    float* msum   = (float*)take(384 * 256 * 4);
    float* rw     = (float*)take(384 * 768 * 4);
    __hip_bfloat16* kv2t = (__hip_bfloat16*)take((size_t)384 * 8192 * 2);
    float* vmeanb = (float*)take(384 * 256 * 4);

    hipMemsetAsync(msum, 0, 384 * 256 * 4, stream);

    prep_weights<<<768, 256, 0, stream>>>(Wq, bq, Wk, bk, Wv, bv, Wo, wqkv, bqkv, wo);
    convert_x<<<dim3(384, 4), 256, 0, stream>>>(x, xb, msum);
    mlp_rw<<<384, 256, 0, stream>>>(msum, w1, b1, w2, b2, rw);
    // QKV projection: [274944,256] x [768,256]^T -> bf16 qkv, bias fused
    gemm_persist<768, true><<<dim3(6, 256), 256, 0, stream>>>(xb, wqkv, bqkv, qkv);
    reduce_kv<<<1536, 512, 0, stream>>>(qkv, kv2t, vmeanb);
    fuse_z2<<<dim3(384, 12), 256, 0, stream>>>(qkv, kv2t, vmeanb, rw, Zbuf);
    // Output projection: [274944,256] x [256,256]^T -> f32 out, bias fused
    gemm_persist<256, false><<<dim3(2, 256), 256, 0, stream>>>(Zbuf, wo, bo, out);
}

// Round 8
// 578.342 us; speedup vs baseline: 1.6174x; 1.2159x over previous
//
#include <hip/hip_runtime.h>
#include <hip/hip_bf16.h>
#include <math.h>

typedef __attribute__((ext_vector_type(8))) short short8;
typedef __attribute__((ext_vector_type(4))) short sv4;
typedef __attribute__((ext_vector_type(4))) float f32x4;
typedef unsigned int u32;

#define BT_ 384
#define N_ 716
#define C_ 256
#define H_ 8
#define D_ 32
#define MROWS (BT_ * N_)   /* 274944 */
#define SCALE_ 0.17677669529663687f  /* 32^-0.5 */
#define INVN_ (1.0f / 716.0f)

__device__ __forceinline__ void gload_lds16(const void* g, void* l) {
    __builtin_amdgcn_global_load_lds(
        (const __attribute__((address_space(1))) u32*)g,
        (__attribute__((address_space(3))) u32*)l, 16, 0, 0);
}

// ---------------------------------------------------------------------------
// Assemble bf16 weight matrices + fused qkv bias. Wqkv_b[768][256], Wo_b[256][256]
// ---------------------------------------------------------------------------
__global__ void prep_weights(const float* __restrict__ Wq, const float* __restrict__ bq,
                             const float* __restrict__ Wk, const float* __restrict__ bk,
                             const float* __restrict__ Wv, const float* __restrict__ bv,
                             const float* __restrict__ Wo,
                             __hip_bfloat16* __restrict__ wqkv, float* __restrict__ bqkv,
                             __hip_bfloat16* __restrict__ wo) {
    int idx = blockIdx.x * 256 + threadIdx.x;
    if (idx < 768 * 256) {
        int o = idx >> 8, c = idx & 255;
        const float* W = (o < 256) ? Wq : ((o < 512) ? Wk : Wv);
        int oo = o & 255;
        wqkv[idx] = __float2bfloat16(W[oo * 256 + c]);
    }
    if (idx < 256 * 256) wo[idx] = __float2bfloat16(Wo[idx]);
    if (idx < 768) bqkv[idx] = (idx < 256) ? bq[idx] : ((idx < 512) ? bk[idx - 256] : bv[idx - 512]);
}

// ---------------------------------------------------------------------------
// x fp32 -> bf16 (vectorized float4/short4), plus per-(bt,channel) col sums
// grid (384, 4), block 256.
// ---------------------------------------------------------------------------
__global__ __launch_bounds__(256)
void convert_x(const float* __restrict__ x, __hip_bfloat16* __restrict__ xb,
               float* __restrict__ msum) {
    int bt = blockIdx.x, chunk = blockIdx.y;
    int t = threadIdx.x;
    int c4 = (t & 63) * 4;
    int r0 = t >> 6;
    size_t base = ((size_t)bt * N_ + (size_t)chunk * 179) * C_;
    float s0 = 0.f, s1 = 0.f, s2 = 0.f, s3 = 0.f;
    for (int r = r0; r < 179; r += 4) {
        float4 f = *(const float4*)&x[base + (size_t)r * C_ + c4];
        union { sv4 v; __hip_bfloat16 h[4]; } u;
        u.h[0] = __float2bfloat16(f.x);
        u.h[1] = __float2bfloat16(f.y);
        u.h[2] = __float2bfloat16(f.z);
        u.h[3] = __float2bfloat16(f.w);
        *(sv4*)&xb[base + (size_t)r * C_ + c4] = u.v;
        s0 += f.x; s1 += f.y; s2 += f.z; s3 += f.w;
    }
    atomicAdd(&msum[bt * C_ + c4 + 0], s0);
    atomicAdd(&msum[bt * C_ + c4 + 1], s1);
    atomicAdd(&msum[bt * C_ + c4 + 2], s2);
    atomicAdd(&msum[bt * C_ + c4 + 3], s3);
}

// ---------------------------------------------------------------------------
// Grouped 2-layer MLP -> per-channel 3-tap conv weights rw[bt][768]
// ---------------------------------------------------------------------------
__global__ __launch_bounds__(256)
void mlp_rw(const float* __restrict__ msum, const float* __restrict__ w1,
            const float* __restrict__ b1, const float* __restrict__ w2,
            const float* __restrict__ b2, float* __restrict__ rw) {
    int bt = blockIdx.x;
    int t = threadIdx.x;
    __shared__ float m_l[256];
    __shared__ float h1_l[256];
    m_l[t] = msum[bt * 256 + t] * INVN_;
    __syncthreads();
    int g = t >> 5;
    float a = b1[t];
    #pragma unroll
    for (int i = 0; i < 32; ++i) a += m_l[g * 32 + i] * w1[t * 32 + i];
    h1_l[t] = 0.5f * a * (1.0f + erff(a * 0.70710678118654752f));
    __syncthreads();
    for (int o = t; o < 768; o += 256) {
        int gg = o / 96;
        float s = b2[o];
        #pragma unroll
        for (int i = 0; i < 32; ++i) s += h1_l[gg * 32 + i] * w2[o * 32 + i];
        rw[bt * 768 + o] = s;
    }
}

// ---------------------------------------------------------------------------
// Persistent B-resident GEMM (unchanged from R7).
// ---------------------------------------------------------------------------
template<int NCOLS, bool OUT_BF16>
__global__ __launch_bounds__(256, 2)
void gemm_persist(const __hip_bfloat16* __restrict__ A, const __hip_bfloat16* __restrict__ Bm,
                  const float* __restrict__ bias, void* __restrict__ outp) {
    __shared__ __align__(16) __hip_bfloat16 As[2][64 * 256];   // 2 x 32KB
    constexpr int NT = MROWS / 64;   // 4296 row-tiles
    const int cb = blockIdx.x;
    const int ib = blockIdx.y;       // 0..255
    const int tid = threadIdx.x;
    const int lane = tid & 63;
    const int wave = tid >> 6;       // 0..3
    const int wm = wave & 1;         // row half (32 rows)
    const int wn = wave >> 1;        // col half (64 cols)
    const int colBase = cb * 128;
    const int l15 = lane & 15, lq = lane >> 4;
    const int lrow2 = lane >> 5;     // 0/1
    const int p = lane & 31;

    auto stageA = [&](int rt, int buf) {
        #pragma unroll
        for (int i = 0; i < 8; ++i) {
            int r = wave * 16 + 2 * i + lrow2;
            const __hip_bfloat16* g = A + ((size_t)rt * 64 + r) * 256 + ((p ^ (r & 7)) * 8);
            gload_lds16(g, &As[buf][(wave * 16 + 2 * i) * 256]);
        }
    };

    stageA(ib, 0);

    short8 bf[4][8];
    #pragma unroll
    for (int n = 0; n < 4; ++n)
        #pragma unroll
        for (int ks = 0; ks < 8; ++ks)
            bf[n][ks] = *(const short8*)&Bm[(size_t)(colBase + wn * 64 + n * 16 + l15) * 256 + ks * 32 + lq * 8];
    float biasr[4];
    #pragma unroll
    for (int n = 0; n < 4; ++n)
        biasr[n] = bias[colBase + wn * 64 + n * 16 + l15];

    asm volatile("s_waitcnt vmcnt(0)" ::: "memory");
    __builtin_amdgcn_s_barrier();

    int buf = 0;
    for (int rt = ib; rt < NT; rt += 256) {
        int rtn = rt + 256;
        if (rtn < NT) stageA(rtn, buf ^ 1);

        f32x4 acc[2][4] = {};
        #pragma unroll
        for (int ks = 0; ks < 8; ++ks) {
            short8 af[2];
            #pragma unroll
            for (int m = 0; m < 2; ++m) {
                int row = wm * 32 + m * 16 + l15;
                af[m] = *(const short8*)&As[buf][row * 256 + (((ks * 4 + lq) ^ (row & 7)) * 8)];
            }
            #pragma unroll
            for (int m = 0; m < 2; ++m)
                #pragma unroll
                for (int n = 0; n < 4; ++n)
                    acc[m][n] = __builtin_amdgcn_mfma_f32_16x16x32_bf16(af[m], bf[n][ks], acc[m][n], 0, 0, 0);
        }
        asm volatile("s_waitcnt lgkmcnt(0)" ::: "memory");
        __builtin_amdgcn_s_barrier();

        if constexpr (OUT_BF16) {
            __hip_bfloat16* Cs = &As[buf][0];  // [64][136]
            #pragma unroll
            for (int m = 0; m < 2; ++m)
                #pragma unroll
                for (int n = 0; n < 4; ++n) {
                    int col = wn * 64 + n * 16 + l15;
                    #pragma unroll
                    for (int j = 0; j < 4; ++j)
                        Cs[(wm * 32 + m * 16 + lq * 4 + j) * 136 + col] =
                            __float2bfloat16(acc[m][n][j] + biasr[n]);
                }
            asm volatile("s_waitcnt lgkmcnt(0)" ::: "memory");
            __builtin_amdgcn_s_barrier();
            int row = tid >> 2, cq = tid & 3;
            __hip_bfloat16* og = (__hip_bfloat16*)outp + ((size_t)rt * 64 + row) * NCOLS + colBase;
            #pragma unroll
            for (int i = 0; i < 4; ++i) {
                int col = cq * 8 + i * 32;
                *(short8*)&og[col] = *(const short8*)&Cs[row * 136 + col];
            }
        } else {
            float* Cs = (float*)&As[buf][0];   // [64][128]
            #pragma unroll
            for (int m = 0; m < 2; ++m)
                #pragma unroll
                for (int n = 0; n < 4; ++n) {
                    int col = wn * 64 + n * 16 + l15;
                    #pragma unroll
                    for (int j = 0; j < 4; ++j)
                        Cs[(wm * 32 + m * 16 + lq * 4 + j) * 128 + col] = acc[m][n][j] + biasr[n];
                }
            asm volatile("s_waitcnt lgkmcnt(0)" ::: "memory");
            __builtin_amdgcn_s_barrier();
            int row = tid >> 2, cq = tid & 3;
            float* og = (float*)outp + ((size_t)rt * 64 + row) * NCOLS + colBase;
            #pragma unroll
            for (int i = 0; i < 8; ++i) {
                int col = cq * 4 + i * 16;
                *(float4*)&og[col] = *(const float4*)&Cs[row * 128 + col];
            }
        }
        asm volatile("s_waitcnt vmcnt(4) lgkmcnt(0)" ::: "memory");
        __builtin_amdgcn_s_barrier();
        buf ^= 1;
    }
}

// ---------------------------------------------------------------------------
// MFMA reduce_kv: one block per bt, 8 waves = 8 heads.
// Per 64-n chunk: stage kT/vT (transposed, slot-XOR swizzled) into LDS via
// reg-staged u32 pair packing; wave h computes kv[32][32] quadrants with
// mfma 16x16x32; ksum/vsum via ones-operand MFMAs (reuse loaded fragments).
// kv2t[bh][e][d] bf16 + vmeanb out. grid 384, block 512.
// ---------------------------------------------------------------------------
__global__ __launch_bounds__(512, 2)
void reduce_kv(const __hip_bfloat16* __restrict__ qkv, __hip_bfloat16* __restrict__ kv2t,
               float* __restrict__ vmeanb) {
    __shared__ __align__(16) __hip_bfloat16 T[512 * 64];   // 64 KB: rows 0..255 kT, 256..511 vT
    const int bt = blockIdx.x;
    const int tid = threadIdx.x;
    const int lane = tid & 63;
    const int h = tid >> 6;            // wave = head
    const int l15 = lane & 15, lq = lane >> 4;
    const int co = tid >> 3;           // 0..63 channel-oct (qkv channels 256+co*8..+8)
    const int np3 = tid & 7;
    const size_t rowbase = (size_t)bt * N_;

    union S8 { short8 v; unsigned short u[8]; };
    const short8 zero8 = {0, 0, 0, 0, 0, 0, 0, 0};

    auto issue_loads = [&](int n0, S8* A, S8* B) {
        #pragma unroll
        for (int s = 0; s < 4; ++s) {
            int n = n0 + 2 * (np3 + 8 * s);
            A[s].v = (n < N_)     ? *(const short8*)&qkv[(rowbase + n) * 768 + 256 + co * 8] : zero8;
            B[s].v = (n + 1 < N_) ? *(const short8*)&qkv[(rowbase + n + 1) * 768 + 256 + co * 8] : zero8;
        }
    };
    auto write_lds = [&](S8* A, S8* B) {
        #pragma unroll
        for (int s = 0; s < 4; ++s) {
            int r = 2 * (np3 + 8 * s);
            int slotbase = ((r >> 3));
            #pragma unroll
            for (int j = 0; j < 8; ++j) {
                int c = co * 8 + j;
                u32 w = (u32)A[s].u[j] | ((u32)B[s].u[j] << 16);
                int off = c * 64 + ((slotbase ^ (c & 7)) << 3) + (r & 7);
                *(u32*)&T[off] = w;
            }
        }
    };

    S8 bufA[4], bufB[4], nxtA[4], nxtB[4];
    issue_loads(0, bufA, bufB);

    f32x4 acc[2][2] = {};
    f32x4 acck[2] = {};
    f32x4 accv[2] = {};
    S8 ones;
    #pragma unroll
    for (int j = 0; j < 8; ++j) ones.u[j] = 0x3F80;   // bf16 1.0

    for (int chunk = 0; chunk < 12; ++chunk) {
        if (chunk < 11) issue_loads((chunk + 1) * 64, nxtA, nxtB);
        write_lds(bufA, bufB);
        __syncthreads();
        #pragma unroll
        for (int nc = 0; nc < 2; ++nc) {
            short8 af[2], bf[2];
            int slot = nc * 4 + lq;
            #pragma unroll
            for (int dh = 0; dh < 2; ++dh) {
                int c = h * 32 + dh * 16 + l15;
                af[dh] = *(const short8*)&T[c * 64 + ((slot ^ (c & 7)) << 3)];
            }
            #pragma unroll
            for (int eh = 0; eh < 2; ++eh) {
                int c = 256 + h * 32 + eh * 16 + l15;
                bf[eh] = *(const short8*)&T[c * 64 + ((slot ^ (c & 7)) << 3)];
            }
            #pragma unroll
            for (int dh = 0; dh < 2; ++dh)
                #pragma unroll
                for (int eh = 0; eh < 2; ++eh)
                    acc[dh][eh] = __builtin_amdgcn_mfma_f32_16x16x32_bf16(af[dh], bf[eh], acc[dh][eh], 0, 0, 0);
            #pragma unroll
            for (int dh = 0; dh < 2; ++dh)
                acck[dh] = __builtin_amdgcn_mfma_f32_16x16x32_bf16(af[dh], ones.v, acck[dh], 0, 0, 0);
            #pragma unroll
            for (int eh = 0; eh < 2; ++eh)
                accv[eh] = __builtin_amdgcn_mfma_f32_16x16x32_bf16(ones.v, bf[eh], accv[eh], 0, 0, 0);
        }
        __syncthreads();
        #pragma unroll
        for (int s = 0; s < 4; ++s) { bufA[s] = nxtA[s]; bufB[s] = nxtB[s]; }
    }

    // epilogue: C layout col = l15, row = lq*4 + j (verified 16x16)
    const int bh = bt * 8 + h;
    #pragma unroll
    for (int eh = 0; eh < 2; ++eh) {
        int e = eh * 16 + l15;
        float vme = accv[eh][0] * INVN_;
        #pragma unroll
        for (int dh = 0; dh < 2; ++dh) {
            union { sv4 v; __hip_bfloat16 x[4]; } o;
            #pragma unroll
            for (int j = 0; j < 4; ++j) {
                float km = acck[dh][j] * INVN_;
                float val = acc[dh][eh][j] * (SCALE_ * INVN_) - SCALE_ * km * vme;
                o.x[j] = __float2bfloat16(val);
            }
            *(sv4*)&kv2t[(size_t)bh * 1024 + e * 32 + dh * 16 + lq * 4] = o.v;
        }
        if (lq == 0) vmeanb[bh * 32 + e] = vme;
    }
}

// ---------------------------------------------------------------------------
// fuse_z2 (unchanged from R6/R7)
// ---------------------------------------------------------------------------
__global__ __launch_bounds__(256)
void fuse_z2(const __hip_bfloat16* __restrict__ qkv, const __hip_bfloat16* __restrict__ kv2t,
             const float* __restrict__ vmeanb, const float* __restrict__ rw,
             __hip_bfloat16* __restrict__ Z) {
    __shared__ __align__(16) __hip_bfloat16 attn[64][256];
    __shared__ __align__(16) __hip_bfloat16 kvl[8192];
    int bt = blockIdx.x;
    int n0 = blockIdx.y * 64;
    int rows = (N_ - n0 < 64) ? (N_ - n0) : 64;
    int t = threadIdx.x;
    const size_t rowbase = (size_t)bt * N_;

    {
        const __hip_bfloat16* src = kv2t + (size_t)bt * 8192;
        #pragma unroll
        for (int i = 0; i < 4; ++i) {
            int off = (t + i * 256) * 8;
            *(short8*)&kvl[off] = *(const short8*)&src[off];
        }
    }
    __syncthreads();

    {
        int lane = t & 63, wave = t >> 6;
        int l15 = lane & 15, lq = lane >> 4;
        int r0 = wave * 16;
        int gn = n0 + r0 + l15; if (gn > N_ - 1) gn = N_ - 1;
        const __hip_bfloat16* qrow = qkv + (rowbase + gn) * 768;
        #pragma unroll
        for (int h = 0; h < 8; ++h) {
            short8 af = *(const short8*)&qrow[h * 32 + lq * 8];
            #pragma unroll
            for (int half = 0; half < 2; ++half) {
                short8 bfr = *(const short8*)&kvl[h * 1024 + (half * 16 + l15) * 32 + lq * 8];
                f32x4 acc = {};
                acc = __builtin_amdgcn_mfma_f32_16x16x32_bf16(af, bfr, acc, 0, 0, 0);
                int col = h * 32 + half * 16 + l15;
                float vm = vmeanb[bt * 256 + col];
                #pragma unroll
                for (int j = 0; j < 4; ++j)
                    attn[r0 + lq * 4 + j][col] = __float2bfloat16(acc[j] + vm);
            }
        }
    }
    __syncthreads();

    {
        int tr = t >> 5;            // 0..7 row sub-range
        int c8 = (t & 31) * 8;      // channel base
        float w0[8], w1_[8], w2_[8];
        #pragma unroll
        for (int u = 0; u < 8; ++u) {
            w0[u]  = rw[bt * 768 + (c8 + u) * 3 + 0];
            w1_[u] = rw[bt * 768 + (c8 + u) * 3 + 1];
            w2_[u] = rw[bt * 768 + (c8 + u) * 3 + 2];
        }
        int rbeg = tr * 8;
        if (rbeg < rows) {
            int rend = rbeg + 8; if (rend > rows) rend = rows;
            union U8 { short8 v; __hip_bfloat16 h[8]; };
            auto loadv = [&](int gn, float* dst) {
                if (gn >= 0 && gn < N_) {
                    U8 u; u.v = *(const short8*)&qkv[(rowbase + gn) * 768 + 512 + c8];
                    #pragma unroll
                    for (int uu = 0; uu < 8; ++uu) dst[uu] = __bfloat162float(u.h[uu]);
                } else {
                    #pragma unroll
                    for (int uu = 0; uu < 8; ++uu) dst[uu] = 0.0f;
                }
            };
            float vprev[8], vcur[8], vnext[8];
            loadv(n0 + rbeg - 1, vprev);
            loadv(n0 + rbeg, vcur);
            for (int r = rbeg; r < rend; ++r) {
                int gn = n0 + r;
                loadv(gn + 1, vnext);
                U8 at; at.v = *(const short8*)&attn[r][c8];
                U8 zv;
                #pragma unroll
                for (int u = 0; u < 8; ++u) {
                    float s = __bfloat162float(at.h[u]) + w0[u] * vprev[u]
                              + w1_[u] * vcur[u] + w2_[u] * vnext[u];
                    zv.h[u] = __float2bfloat16(s);
                }
                *(short8*)&Z[(rowbase + gn) * 256 + c8] = zv.v;
                #pragma unroll
                for (int u = 0; u < 8; ++u) { vprev[u] = vcur[u]; vcur[u] = vnext[u]; }
            }
        }
    }
}

// ---------------------------------------------------------------------------
extern "C" void kernel_launch(void* const* d_in, const int* in_sizes, int n_in,
                              void* d_out, int out_size, void* d_ws, size_t ws_size,
                              hipStream_t stream) {
    (void)in_sizes; (void)n_in; (void)out_size; (void)ws_size;
    const float* x  = (const float*)d_in[0];
    const float* Wq = (const float*)d_in[1];  const float* bq = (const float*)d_in[2];
    const float* Wk = (const float*)d_in[3];  const float* bk = (const float*)d_in[4];
    const float* Wv = (const float*)d_in[5];  const float* bv = (const float*)d_in[6];
    const float* Wo = (const float*)d_in[7];  const float* bo = (const float*)d_in[8];
    const float* w1 = (const float*)d_in[9];  const float* b1 = (const float*)d_in[10];
    const float* w2 = (const float*)d_in[11]; const float* b2 = (const float*)d_in[12];
    float* out = (float*)d_out;

    char* ws = (char*)d_ws;
    size_t off = 0;
    auto take = [&](size_t bytes) -> char* {
        char* p = ws + off;
        off = (off + bytes + 255) & ~(size_t)255;
        return p;
    };

    __hip_bfloat16* qkv   = (__hip_bfloat16*)take((size_t)MROWS * 768 * 2);
    __hip_bfloat16* xb    = (__hip_bfloat16*)take((size_t)MROWS * 256 * 2);
    __hip_bfloat16* Zbuf  = xb;  // alias: xb dead after gemm_qkv, reused for Z
    __hip_bfloat16* wqkv  = (__hip_bfloat16*)take(768 * 256 * 2);
    __hip_bfloat16* wo    = (__hip_bfloat16*)take(256 * 256 * 2);
    float* bqkv   = (float*)take(768 * 4);
    float* msum   = (float*)take(384 * 256 * 4);
    float* rw     = (float*)take(384 * 768 * 4);
    __hip_bfloat16* kv2t = (__hip_bfloat16*)take((size_t)384 * 8192 * 2);
    float* vmeanb = (float*)take(384 * 256 * 4);

    hipMemsetAsync(msum, 0, 384 * 256 * 4, stream);

    prep_weights<<<768, 256, 0, stream>>>(Wq, bq, Wk, bk, Wv, bv, Wo, wqkv, bqkv, wo);
    convert_x<<<dim3(384, 4), 256, 0, stream>>>(x, xb, msum);
    mlp_rw<<<384, 256, 0, stream>>>(msum, w1, b1, w2, b2, rw);
    // QKV projection: [274944,256] x [768,256]^T -> bf16 qkv, bias fused
    gemm_persist<768, true><<<dim3(6, 256), 256, 0, stream>>>(xb, wqkv, bqkv, qkv);
    reduce_kv<<<384, 512, 0, stream>>>(qkv, kv2t, vmeanb);
    fuse_z2<<<dim3(384, 12), 256, 0, stream>>>(qkv, kv2t, vmeanb, rw, Zbuf);
    // Output projection: [274944,256] x [256,256]^T -> f32 out, bias fused
    gemm_persist<256, false><<<dim3(2, 256), 256, 0, stream>>>(Zbuf, wo, bo, out);
}

// Round 9
// 543.761 us; speedup vs baseline: 1.7202x; 1.0636x over previous
//
#include <hip/hip_runtime.h>
#include <hip/hip_bf16.h>
#include <math.h>

typedef __attribute__((ext_vector_type(8))) short short8;
typedef __attribute__((ext_vector_type(4))) short sv4;
typedef __attribute__((ext_vector_type(4))) float f32x4;
typedef unsigned int u32;

#define BT_ 384
#define N_ 716
#define C_ 256
#define H_ 8
#define D_ 32
#define MROWS (BT_ * N_)   /* 274944 */
#define SCALE_ 0.17677669529663687f  /* 32^-0.5 */
#define INVN_ (1.0f / 716.0f)

__device__ __forceinline__ void gload_lds16(const void* g, void* l) {
    __builtin_amdgcn_global_load_lds(
        (const __attribute__((address_space(1))) u32*)g,
        (__attribute__((address_space(3))) u32*)l, 16, 0, 0);
}

// ---------------------------------------------------------------------------
// Assemble bf16 weight matrices + fused qkv bias. Wqkv_b[768][256], Wo_b[256][256]
// ---------------------------------------------------------------------------
__global__ void prep_weights(const float* __restrict__ Wq, const float* __restrict__ bq,
                             const float* __restrict__ Wk, const float* __restrict__ bk,
                             const float* __restrict__ Wv, const float* __restrict__ bv,
                             const float* __restrict__ Wo,
                             __hip_bfloat16* __restrict__ wqkv, float* __restrict__ bqkv,
                             __hip_bfloat16* __restrict__ wo) {
    int idx = blockIdx.x * 256 + threadIdx.x;
    if (idx < 768 * 256) {
        int o = idx >> 8, c = idx & 255;
        const float* W = (o < 256) ? Wq : ((o < 512) ? Wk : Wv);
        int oo = o & 255;
        wqkv[idx] = __float2bfloat16(W[oo * 256 + c]);
    }
    if (idx < 256 * 256) wo[idx] = __float2bfloat16(Wo[idx]);
    if (idx < 768) bqkv[idx] = (idx < 256) ? bq[idx] : ((idx < 512) ? bk[idx - 256] : bv[idx - 512]);
}

// ---------------------------------------------------------------------------
// x fp32 -> bf16 (vectorized float4/short4), plus per-(bt,channel) col sums
// grid (384, 4), block 256.
// ---------------------------------------------------------------------------
__global__ __launch_bounds__(256)
void convert_x(const float* __restrict__ x, __hip_bfloat16* __restrict__ xb,
               float* __restrict__ msum) {
    int bt = blockIdx.x, chunk = blockIdx.y;
    int t = threadIdx.x;
    int c4 = (t & 63) * 4;
    int r0 = t >> 6;
    size_t base = ((size_t)bt * N_ + (size_t)chunk * 179) * C_;
    float s0 = 0.f, s1 = 0.f, s2 = 0.f, s3 = 0.f;
    for (int r = r0; r < 179; r += 4) {
        float4 f = *(const float4*)&x[base + (size_t)r * C_ + c4];
        union { sv4 v; __hip_bfloat16 h[4]; } u;
        u.h[0] = __float2bfloat16(f.x);
        u.h[1] = __float2bfloat16(f.y);
        u.h[2] = __float2bfloat16(f.z);
        u.h[3] = __float2bfloat16(f.w);
        *(sv4*)&xb[base + (size_t)r * C_ + c4] = u.v;
        s0 += f.x; s1 += f.y; s2 += f.z; s3 += f.w;
    }
    atomicAdd(&msum[bt * C_ + c4 + 0], s0);
    atomicAdd(&msum[bt * C_ + c4 + 1], s1);
    atomicAdd(&msum[bt * C_ + c4 + 2], s2);
    atomicAdd(&msum[bt * C_ + c4 + 3], s3);
}

// ---------------------------------------------------------------------------
// Grouped 2-layer MLP -> per-channel 3-tap conv weights rw[bt][768]
// ---------------------------------------------------------------------------
__global__ __launch_bounds__(256)
void mlp_rw(const float* __restrict__ msum, const float* __restrict__ w1,
            const float* __restrict__ b1, const float* __restrict__ w2,
            const float* __restrict__ b2, float* __restrict__ rw) {
    int bt = blockIdx.x;
    int t = threadIdx.x;
    __shared__ float m_l[256];
    __shared__ float h1_l[256];
    m_l[t] = msum[bt * 256 + t] * INVN_;
    __syncthreads();
    int g = t >> 5;
    float a = b1[t];
    #pragma unroll
    for (int i = 0; i < 32; ++i) a += m_l[g * 32 + i] * w1[t * 32 + i];
    h1_l[t] = 0.5f * a * (1.0f + erff(a * 0.70710678118654752f));
    __syncthreads();
    for (int o = t; o < 768; o += 256) {
        int gg = o / 96;
        float s = b2[o];
        #pragma unroll
        for (int i = 0; i < 32; ++i) s += h1_l[gg * 32 + i] * w2[o * 32 + i];
        rw[bt * 768 + o] = s;
    }
}

// ---------------------------------------------------------------------------
// Persistent B-resident GEMM v2: out[m][o] = sum_k A[m][k]*Bm[o][k] + bias[o]
// 4 waves, wave tile 64x32 -> bf[2][8] = 64 VGPR (fits; no spill).
// XCD-aware 1D grid: all col-blocks of a stripe on ONE XCD (A fetched once).
// A double-buffered 64KB LDS, XOR swizzle, counted vmcnt. fp32 epilogue in
// two 32-row passes with padded stride (conflict-free, fits dead buffer).
// grid GRIDX*256 (1D), block 256.
// ---------------------------------------------------------------------------
template<int NCOLS, int GRIDX, bool OUT_BF16>
__global__ __launch_bounds__(256, 2)
void gemm_persist(const __hip_bfloat16* __restrict__ A, const __hip_bfloat16* __restrict__ Bm,
                  const float* __restrict__ bias, void* __restrict__ outp) {
    __shared__ __align__(16) __hip_bfloat16 As[2][64 * 256];   // 2 x 32KB
    constexpr int NT = MROWS / 64;   // 4296 row-tiles
    const int L = blockIdx.x;
    const int xcd = L & 7, w = L >> 3;
    const int cb = w % GRIDX;
    const int ib = xcd * 32 + w / GRIDX;    // stripe 0..255; all cb of ib share xcd
    const int tid = threadIdx.x;
    const int lane = tid & 63;
    const int wave = tid >> 6;       // 0..3
    const int wn = wave;             // col quarter (32 cols)
    const int colBase = cb * 128;
    const int l15 = lane & 15, lq = lane >> 4;
    const int lrow2 = lane >> 5;     // 0/1
    const int p = lane & 31;

    auto stageA = [&](int rt, int buf) {
        #pragma unroll
        for (int i = 0; i < 8; ++i) {
            int r = wave * 16 + 2 * i + lrow2;
            const __hip_bfloat16* g = A + ((size_t)rt * 64 + r) * 256 + ((p ^ (r & 7)) * 8);
            gload_lds16(g, &As[buf][(wave * 16 + 2 * i) * 256]);
        }
    };

    stageA(ib, 0);

    // B fragments in registers: 2 x 8 x short8 = 64 VGPR (loop-invariant)
    short8 bf[2][8];
    #pragma unroll
    for (int n = 0; n < 2; ++n)
        #pragma unroll
        for (int ks = 0; ks < 8; ++ks)
            bf[n][ks] = *(const short8*)&Bm[(size_t)(colBase + wn * 32 + n * 16 + l15) * 256 + ks * 32 + lq * 8];
    float biasr[2];
    #pragma unroll
    for (int n = 0; n < 2; ++n)
        biasr[n] = bias[colBase + wn * 32 + n * 16 + l15];

    asm volatile("s_waitcnt vmcnt(0)" ::: "memory");
    __builtin_amdgcn_s_barrier();

    int buf = 0;
    for (int rt = ib; rt < NT; rt += 256) {
        int rtn = rt + 256;
        if (rtn < NT) stageA(rtn, buf ^ 1);

        // compute 64x128: wave computes rows 0..63 x cols wn*32..+32
        f32x4 acc[4][2] = {};
        #pragma unroll
        for (int ks = 0; ks < 8; ++ks) {
            short8 af[4];
            #pragma unroll
            for (int m = 0; m < 4; ++m) {
                int row = m * 16 + l15;
                af[m] = *(const short8*)&As[buf][row * 256 + (((ks * 4 + lq) ^ (row & 7)) * 8)];
            }
            #pragma unroll
            for (int m = 0; m < 4; ++m)
                #pragma unroll
                for (int n = 0; n < 2; ++n)
                    acc[m][n] = __builtin_amdgcn_mfma_f32_16x16x32_bf16(af[m], bf[n][ks], acc[m][n], 0, 0, 0);
        }
        asm volatile("s_waitcnt lgkmcnt(0)" ::: "memory");
        __builtin_amdgcn_s_barrier();          // all waves done reading As[buf]

        if constexpr (OUT_BF16) {
            __hip_bfloat16* Cs = &As[buf][0];  // [64][136], 17.4KB
            #pragma unroll
            for (int m = 0; m < 4; ++m)
                #pragma unroll
                for (int n = 0; n < 2; ++n) {
                    int col = wn * 32 + n * 16 + l15;
                    #pragma unroll
                    for (int j = 0; j < 4; ++j)
                        Cs[(m * 16 + lq * 4 + j) * 136 + col] =
                            __float2bfloat16(acc[m][n][j] + biasr[n]);
                }
            asm volatile("s_waitcnt lgkmcnt(0)" ::: "memory");
            __builtin_amdgcn_s_barrier();
            int row = tid >> 2, cq = tid & 3;
            __hip_bfloat16* og = (__hip_bfloat16*)outp + ((size_t)rt * 64 + row) * NCOLS + colBase;
            #pragma unroll
            for (int i = 0; i < 4; ++i) {
                int col = cq * 8 + i * 32;
                *(short8*)&og[col] = *(const short8*)&Cs[row * 136 + col];
            }
        } else {
            float* Cs = (float*)&As[buf][0];   // [32][132] per pass, 16.9KB
            #pragma unroll
            for (int pp = 0; pp < 2; ++pp) {
                #pragma unroll
                for (int mm = 0; mm < 2; ++mm) {
                    int m = 2 * pp + mm;
                    #pragma unroll
                    for (int n = 0; n < 2; ++n) {
                        int col = wn * 32 + n * 16 + l15;
                        #pragma unroll
                        for (int j = 0; j < 4; ++j)
                            Cs[(mm * 16 + lq * 4 + j) * 132 + col] = acc[m][n][j] + biasr[n];
                    }
                }
                asm volatile("s_waitcnt lgkmcnt(0)" ::: "memory");
                __builtin_amdgcn_s_barrier();
                int row = tid >> 3, k = tid & 7;
                float* og = (float*)outp + ((size_t)rt * 64 + pp * 32 + row) * NCOLS + colBase;
                #pragma unroll
                for (int i = 0; i < 4; ++i) {
                    int col = k * 4 + i * 32;
                    *(float4*)&og[col] = *(const float4*)&Cs[row * 132 + col];
                }
                asm volatile("s_waitcnt lgkmcnt(0)" ::: "memory");
                __builtin_amdgcn_s_barrier();
            }
        }
        // stage loads (oldest) must land; stores may stay in flight
        asm volatile("s_waitcnt vmcnt(4) lgkmcnt(0)" ::: "memory");
        __builtin_amdgcn_s_barrier();
        buf ^= 1;
    }
}

// ---------------------------------------------------------------------------
// MFMA reduce_kv (unchanged from R8): one block per bt, 8 waves = 8 heads.
// ---------------------------------------------------------------------------
__global__ __launch_bounds__(512, 2)
void reduce_kv(const __hip_bfloat16* __restrict__ qkv, __hip_bfloat16* __restrict__ kv2t,
               float* __restrict__ vmeanb) {
    __shared__ __align__(16) __hip_bfloat16 T[512 * 64];   // 64 KB
    const int bt = blockIdx.x;
    const int tid = threadIdx.x;
    const int lane = tid & 63;
    const int h = tid >> 6;
    const int l15 = lane & 15, lq = lane >> 4;
    const int co = tid >> 3;
    const int np3 = tid & 7;
    const size_t rowbase = (size_t)bt * N_;

    union S8 { short8 v; unsigned short u[8]; };
    const short8 zero8 = {0, 0, 0, 0, 0, 0, 0, 0};

    auto issue_loads = [&](int n0, S8* A, S8* B) {
        #pragma unroll
        for (int s = 0; s < 4; ++s) {
            int n = n0 + 2 * (np3 + 8 * s);
            A[s].v = (n < N_)     ? *(const short8*)&qkv[(rowbase + n) * 768 + 256 + co * 8] : zero8;
            B[s].v = (n + 1 < N_) ? *(const short8*)&qkv[(rowbase + n + 1) * 768 + 256 + co * 8] : zero8;
        }
    };
    auto write_lds = [&](S8* A, S8* B) {
        #pragma unroll
        for (int s = 0; s < 4; ++s) {
            int r = 2 * (np3 + 8 * s);
            int slotbase = ((r >> 3));
            #pragma unroll
            for (int j = 0; j < 8; ++j) {
                int c = co * 8 + j;
                u32 w = (u32)A[s].u[j] | ((u32)B[s].u[j] << 16);
                int off = c * 64 + ((slotbase ^ (c & 7)) << 3) + (r & 7);
                *(u32*)&T[off] = w;
            }
        }
    };

    S8 bufA[4], bufB[4], nxtA[4], nxtB[4];
    issue_loads(0, bufA, bufB);

    f32x4 acc[2][2] = {};
    f32x4 acck[2] = {};
    f32x4 accv[2] = {};
    S8 ones;
    #pragma unroll
    for (int j = 0; j < 8; ++j) ones.u[j] = 0x3F80;   // bf16 1.0

    for (int chunk = 0; chunk < 12; ++chunk) {
        if (chunk < 11) issue_loads((chunk + 1) * 64, nxtA, nxtB);
        write_lds(bufA, bufB);
        __syncthreads();
        #pragma unroll
        for (int nc = 0; nc < 2; ++nc) {
            short8 af[2], bf[2];
            int slot = nc * 4 + lq;
            #pragma unroll
            for (int dh = 0; dh < 2; ++dh) {
                int c = h * 32 + dh * 16 + l15;
                af[dh] = *(const short8*)&T[c * 64 + ((slot ^ (c & 7)) << 3)];
            }
            #pragma unroll
            for (int eh = 0; eh < 2; ++eh) {
                int c = 256 + h * 32 + eh * 16 + l15;
                bf[eh] = *(const short8*)&T[c * 64 + ((slot ^ (c & 7)) << 3)];
            }
            #pragma unroll
            for (int dh = 0; dh < 2; ++dh)
                #pragma unroll
                for (int eh = 0; eh < 2; ++eh)
                    acc[dh][eh] = __builtin_amdgcn_mfma_f32_16x16x32_bf16(af[dh], bf[eh], acc[dh][eh], 0, 0, 0);
            #pragma unroll
            for (int dh = 0; dh < 2; ++dh)
                acck[dh] = __builtin_amdgcn_mfma_f32_16x16x32_bf16(af[dh], ones.v, acck[dh], 0, 0, 0);
            #pragma unroll
            for (int eh = 0; eh < 2; ++eh)
                accv[eh] = __builtin_amdgcn_mfma_f32_16x16x32_bf16(ones.v, bf[eh], accv[eh], 0, 0, 0);
        }
        __syncthreads();
        #pragma unroll
        for (int s = 0; s < 4; ++s) { bufA[s] = nxtA[s]; bufB[s] = nxtB[s]; }
    }

    const int bh = bt * 8 + h;
    #pragma unroll
    for (int eh = 0; eh < 2; ++eh) {
        int e = eh * 16 + l15;
        float vme = accv[eh][0] * INVN_;
        #pragma unroll
        for (int dh = 0; dh < 2; ++dh) {
            union { sv4 v; __hip_bfloat16 x[4]; } o;
            #pragma unroll
            for (int j = 0; j < 4; ++j) {
                float km = acck[dh][j] * INVN_;
                float val = acc[dh][eh][j] * (SCALE_ * INVN_) - SCALE_ * km * vme;
                o.x[j] = __float2bfloat16(val);
            }
            *(sv4*)&kv2t[(size_t)bh * 1024 + e * 32 + dh * 16 + lq * 4] = o.v;
        }
        if (lq == 0) vmeanb[bh * 32 + e] = vme;
    }
}

// ---------------------------------------------------------------------------
// fuse_z2 (unchanged)
// ---------------------------------------------------------------------------
__global__ __launch_bounds__(256)
void fuse_z2(const __hip_bfloat16* __restrict__ qkv, const __hip_bfloat16* __restrict__ kv2t,
             const float* __restrict__ vmeanb, const float* __restrict__ rw,
             __hip_bfloat16* __restrict__ Z) {
    __shared__ __align__(16) __hip_bfloat16 attn[64][256];
    __shared__ __align__(16) __hip_bfloat16 kvl[8192];
    int bt = blockIdx.x;
    int n0 = blockIdx.y * 64;
    int rows = (N_ - n0 < 64) ? (N_ - n0) : 64;
    int t = threadIdx.x;
    const size_t rowbase = (size_t)bt * N_;

    {
        const __hip_bfloat16* src = kv2t + (size_t)bt * 8192;
        #pragma unroll
        for (int i = 0; i < 4; ++i) {
            int off = (t + i * 256) * 8;
            *(short8*)&kvl[off] = *(const short8*)&src[off];
        }
    }
    __syncthreads();

    {
        int lane = t & 63, wave = t >> 6;
        int l15 = lane & 15, lq = lane >> 4;
        int r0 = wave * 16;
        int gn = n0 + r0 + l15; if (gn > N_ - 1) gn = N_ - 1;
        const __hip_bfloat16* qrow = qkv + (rowbase + gn) * 768;
        #pragma unroll
        for (int h = 0; h < 8; ++h) {
            short8 af = *(const short8*)&qrow[h * 32 + lq * 8];
            #pragma unroll
            for (int half = 0; half < 2; ++half) {
                short8 bfr = *(const short8*)&kvl[h * 1024 + (half * 16 + l15) * 32 + lq * 8];
                f32x4 acc = {};
                acc = __builtin_amdgcn_mfma_f32_16x16x32_bf16(af, bfr, acc, 0, 0, 0);
                int col = h * 32 + half * 16 + l15;
                float vm = vmeanb[bt * 256 + col];
                #pragma unroll
                for (int j = 0; j < 4; ++j)
                    attn[r0 + lq * 4 + j][col] = __float2bfloat16(acc[j] + vm);
            }
        }
    }
    __syncthreads();

    {
        int tr = t >> 5;
        int c8 = (t & 31) * 8;
        float w0[8], w1_[8], w2_[8];
        #pragma unroll
        for (int u = 0; u < 8; ++u) {
            w0[u]  = rw[bt * 768 + (c8 + u) * 3 + 0];
            w1_[u] = rw[bt * 768 + (c8 + u) * 3 + 1];
            w2_[u] = rw[bt * 768 + (c8 + u) * 3 + 2];
        }
        int rbeg = tr * 8;
        if (rbeg < rows) {
            int rend = rbeg + 8; if (rend > rows) rend = rows;
            union U8 { short8 v; __hip_bfloat16 h[8]; };
            auto loadv = [&](int gn, float* dst) {
                if (gn >= 0 && gn < N_) {
                    U8 u; u.v = *(const short8*)&qkv[(rowbase + gn) * 768 + 512 + c8];
                    #pragma unroll
                    for (int uu = 0; uu < 8; ++uu) dst[uu] = __bfloat162float(u.h[uu]);
                } else {
                    #pragma unroll
                    for (int uu = 0; uu < 8; ++uu) dst[uu] = 0.0f;
                }
            };
            float vprev[8], vcur[8], vnext[8];
            loadv(n0 + rbeg - 1, vprev);
            loadv(n0 + rbeg, vcur);
            for (int r = rbeg; r < rend; ++r) {
                int gn = n0 + r;
                loadv(gn + 1, vnext);
                U8 at; at.v = *(const short8*)&attn[r][c8];
                U8 zv;
                #pragma unroll
                for (int u = 0; u < 8; ++u) {
                    float s = __bfloat162float(at.h[u]) + w0[u] * vprev[u]
                              + w1_[u] * vcur[u] + w2_[u] * vnext[u];
                    zv.h[u] = __float2bfloat16(s);
                }
                *(short8*)&Z[(rowbase + gn) * 256 + c8] = zv.v;
                #pragma unroll
                for (int u = 0; u < 8; ++u) { vprev[u] = vcur[u]; vcur[u] = vnext[u]; }
            }
        }
    }
}

// ---------------------------------------------------------------------------
extern "C" void kernel_launch(void* const* d_in, const int* in_sizes, int n_in,
                              void* d_out, int out_size, void* d_ws, size_t ws_size,
                              hipStream_t stream) {
    (void)in_sizes; (void)n_in; (void)out_size; (void)ws_size;
    const float* x  = (const float*)d_in[0];
    const float* Wq = (const float*)d_in[1];  const float* bq = (const float*)d_in[2];
    const float* Wk = (const float*)d_in[3];  const float* bk = (const float*)d_in[4];
    const float* Wv = (const float*)d_in[5];  const float* bv = (const float*)d_in[6];
    const float* Wo = (const float*)d_in[7];  const float* bo = (const float*)d_in[8];
    const float* w1 = (const float*)d_in[9];  const float* b1 = (const float*)d_in[10];
    const float* w2 = (const float*)d_in[11]; const float* b2 = (const float*)d_in[12];
    float* out = (float*)d_out;

    char* ws = (char*)d_ws;
    size_t off = 0;
    auto take = [&](size_t bytes) -> char* {
        char* p = ws + off;
        off = (off + bytes + 255) & ~(size_t)255;
        return p;
    };

    __hip_bfloat16* qkv   = (__hip_bfloat16*)take((size_t)MROWS * 768 * 2);
    __hip_bfloat16* xb    = (__hip_bfloat16*)take((size_t)MROWS * 256 * 2);
    __hip_bfloat16* Zbuf  = xb;  // alias: xb dead after gemm_qkv, reused for Z
    __hip_bfloat16* wqkv  = (__hip_bfloat16*)take(768 * 256 * 2);
    __hip_bfloat16* wo    = (__hip_bfloat16*)take(256 * 256 * 2);
    float* bqkv   = (float*)take(768 * 4);
    float* msum   = (float*)take(384 * 256 * 4);
    float* rw     = (float*)take(384 * 768 * 4);
    __hip_bfloat16* kv2t = (__hip_bfloat16*)take((size_t)384 * 8192 * 2);
    float* vmeanb = (float*)take(384 * 256 * 4);

    hipMemsetAsync(msum, 0, 384 * 256 * 4, stream);

    prep_weights<<<768, 256, 0, stream>>>(Wq, bq, Wk, bk, Wv, bv, Wo, wqkv, bqkv, wo);
    convert_x<<<dim3(384, 4), 256, 0, stream>>>(x, xb, msum);
    mlp_rw<<<384, 256, 0, stream>>>(msum, w1, b1, w2, b2, rw);
    // QKV projection: [274944,256] x [768,256]^T -> bf16 qkv, bias fused
    gemm_persist<768, 6, true><<<1536, 256, 0, stream>>>(xb, wqkv, bqkv, qkv);
    reduce_kv<<<384, 512, 0, stream>>>(qkv, kv2t, vmeanb);
    fuse_z2<<<dim3(384, 12), 256, 0, stream>>>(qkv, kv2t, vmeanb, rw, Zbuf);
    // Output projection: [274944,256] x [256,256]^T -> f32 out, bias fused
    gemm_persist<256, 2, false><<<512, 256, 0, stream>>>(Zbuf, wo, bo, out);
}